// Round 1
// baseline (325.306 us; speedup 1.0000x reference)
//
#include <hip/hip_runtime.h>
#include <hip/hip_bf16.h>
#include <stdint.h>

typedef __hip_bfloat16 bf16;
typedef short bf16x8 __attribute__((ext_vector_type(8)));
typedef float f32x4 __attribute__((ext_vector_type(4)));

#define NTOK 2048
#define HIDDEN 2880
#define QKVN 5120
#define QSZ 4096
#define NH 64
#define NKV 8
#define HD 64
#define SEQ 1024

__device__ __forceinline__ void gload16(const void* g, void* l) {
  __builtin_amdgcn_global_load_lds(
      (const __attribute__((address_space(1))) uint32_t*)g,
      (__attribute__((address_space(3))) uint32_t*)l, 16, 0, 0);
}

// ---------------- fp32 -> bf16 elementwise ----------------
__global__ __launch_bounds__(256) void cvt_f32_bf16_k(const float* __restrict__ src,
                                                      bf16* __restrict__ dst, int n4) {
  int i = blockIdx.x * 256 + threadIdx.x;
  if (i >= n4) return;
  const float4 v = reinterpret_cast<const float4*>(src)[i];
  bf16 o[4] = {__float2bfloat16(v.x), __float2bfloat16(v.y),
               __float2bfloat16(v.z), __float2bfloat16(v.w)};
  reinterpret_cast<uint2*>(dst)[i] = *reinterpret_cast<const uint2*>(o);
}

// ---------------- src[R][C] f32 -> dst[C][R] bf16 (tiled transpose) ----------------
__global__ __launch_bounds__(256) void transpose_cvt_k(const float* __restrict__ src,
                                                       bf16* __restrict__ dst, int R, int C) {
  __shared__ float t[32][33];
  int c0 = blockIdx.x * 32, r0 = blockIdx.y * 32;
  int tx = threadIdx.x, ty = threadIdx.y;
#pragma unroll
  for (int i = 0; i < 4; ++i)
    t[ty + i * 8][tx] = src[(size_t)(r0 + ty + i * 8) * C + c0 + tx];
  __syncthreads();
#pragma unroll
  for (int i = 0; i < 4; ++i)
    dst[(size_t)(c0 + ty + i * 8) * R + r0 + tx] = __float2bfloat16(t[tx][ty + i * 8]);
}

// ---------------- bf16 GEMM: A[M][K] * BT[N][K]^T -> C[M][N] fp32 ----------------
// m97 structure: 128x128 tile, BK=64, 4 waves (2x2 of 64x64), global_load_lds w=16.
__global__ __launch_bounds__(256) void gemm_bt_k(const bf16* __restrict__ A,
                                                 const bf16* __restrict__ BT,
                                                 float* __restrict__ C,
                                                 int M, int N, int K, int nbn) {
  __shared__ __align__(16) bf16 As[128 * 64];
  __shared__ __align__(16) bf16 Bs[128 * 64];
  int bm = blockIdx.x / nbn, bn = blockIdx.x % nbn;
  int m0 = bm * 128, n0 = bn * 128;
  int tid = threadIdx.x, w = tid >> 6, l = tid & 63, lg = l >> 4, lm = l & 15;
  int wm = (w >> 1) * 64, wn = (w & 1) * 64;
  f32x4 acc[4][4] = {};
  for (int k0 = 0; k0 < K; k0 += 64) {
#pragma unroll
    for (int g = 0; g < 4; ++g) {
      int c = g * 256 + w * 64 + l;
      int r = c >> 3, kc = (c & 7) * 8;
      int ar = m0 + r; if (ar > M - 1) ar = M - 1;
      int br = n0 + r; if (br > N - 1) br = N - 1;
      gload16(A + (size_t)ar * K + k0 + kc, (char*)As + (size_t)(g * 256 + w * 64) * 16);
      gload16(BT + (size_t)br * K + k0 + kc, (char*)Bs + (size_t)(g * 256 + w * 64) * 16);
    }
    __syncthreads();
#pragma unroll
    for (int kk = 0; kk < 2; ++kk) {
      bf16x8 af[4], bfv[4];
#pragma unroll
      for (int mi = 0; mi < 4; ++mi)
        af[mi] = *reinterpret_cast<const bf16x8*>(&As[(wm + mi * 16 + lm) * 64 + kk * 32 + lg * 8]);
#pragma unroll
      for (int ni = 0; ni < 4; ++ni)
        bfv[ni] = *reinterpret_cast<const bf16x8*>(&Bs[(wn + ni * 16 + lm) * 64 + kk * 32 + lg * 8]);
#pragma unroll
      for (int mi = 0; mi < 4; ++mi)
#pragma unroll
        for (int ni = 0; ni < 4; ++ni)
          acc[mi][ni] = __builtin_amdgcn_mfma_f32_16x16x32_bf16(af[mi], bfv[ni], acc[mi][ni], 0, 0, 0);
    }
    __syncthreads();
  }
#pragma unroll
  for (int mi = 0; mi < 4; ++mi)
#pragma unroll
    for (int ni = 0; ni < 4; ++ni) {
      int col = n0 + wn + ni * 16 + lm;
      if (col >= N) continue;
      int row = m0 + wm + mi * 16 + lg * 4;
#pragma unroll
      for (int j = 0; j < 4; ++j)
        if (row + j < M) C[(size_t)(row + j) * N + col] = acc[mi][ni][j];
    }
}

// ---------------- RoPE + layout: qkv f32 -> q(scaled) bf16, k bf16, v^T bf16 ----------------
__global__ __launch_bounds__(256) void rope_k(const float* __restrict__ qkv,
                                              const int* __restrict__ positions,
                                              bf16* __restrict__ qo,   // [2048][4096]
                                              bf16* __restrict__ ko,   // [2048][512]
                                              bf16* __restrict__ vT) { // [(b*8+kvh)*64+d][1024]
  __shared__ float cs[32], sn[32];
  int t = blockIdx.x;
  int tid = threadIdx.x;
  if (tid < 32) {
    float inv = __expf(-(float)tid * (logf(150000.0f) / 32.0f));
    float a = (float)positions[t] * inv;
    cs[tid] = cosf(a);
    sn[tid] = sinf(a);
  }
  __syncthreads();
  const float* row = qkv + (size_t)t * QKVN;
#pragma unroll
  for (int p = tid; p < NH * 32; p += 256) {
    int h = p >> 5, d = p & 31;
    float x1 = row[h * 64 + d], x2 = row[h * 64 + d + 32];
    qo[(size_t)t * QSZ + h * 64 + d]      = __float2bfloat16((x1 * cs[d] - x2 * sn[d]) * 0.125f);
    qo[(size_t)t * QSZ + h * 64 + d + 32] = __float2bfloat16((x2 * cs[d] + x1 * sn[d]) * 0.125f);
  }
  {
    int p = tid;  // 8 kv heads * 32 = 256 exactly
    int kvh = p >> 5, d = p & 31;
    float x1 = row[QSZ + kvh * 64 + d], x2 = row[QSZ + kvh * 64 + d + 32];
    ko[(size_t)t * 512 + kvh * 64 + d]      = __float2bfloat16(x1 * cs[d] - x2 * sn[d]);
    ko[(size_t)t * 512 + kvh * 64 + d + 32] = __float2bfloat16(x2 * cs[d] + x1 * sn[d]);
  }
  int b = t >> 10, s = t & 1023;
#pragma unroll
  for (int p = tid; p < 512; p += 256) {
    int kvh = p >> 6, d = p & 63;
    vT[((size_t)(b * 8 + kvh) * 64 + d) * 1024 + s] = __float2bfloat16(row[4608 + kvh * 64 + d]);
  }
}

// ---------------- flash attention, sliding window 128, sinks ----------------
// block = (b, h, q-tile of 128). 4 waves; wave w: queries w*32..w*32+31, all 128 keys of tile.
__global__ __launch_bounds__(256) void attn_k(const bf16* __restrict__ Q,
                                              const bf16* __restrict__ Kg,
                                              const bf16* __restrict__ VT,
                                              const float* __restrict__ sinks,
                                              bf16* __restrict__ Og) {
  __shared__ __align__(16) bf16 Qs[128 * 64];
  __shared__ __align__(16) bf16 Ks[128 * 64];
  __shared__ __align__(16) bf16 Vs[64 * 128];
  __shared__ __align__(16) bf16 Ps[4][32 * 128];
  int bid = blockIdx.x;
  int b = bid >> 9, rest = bid & 511, h = rest >> 3, qt = rest & 7;
  int q0 = qt * 128, kvh = h >> 3;
  int tid = threadIdx.x, w = tid >> 6, l = tid & 63, lg = l >> 4, lm = l & 15;

  float mrun[2][4], lrun[2][4];
  float ls = __logf(sinks[h]);  // sink folded exactly into online-softmax init
#pragma unroll
  for (int mi = 0; mi < 2; ++mi)
#pragma unroll
    for (int j = 0; j < 4; ++j) { mrun[mi][j] = ls; lrun[mi][j] = 1.0f; }
  f32x4 oacc[2][4] = {};

#pragma unroll
  for (int g = 0; g < 4; ++g) {
    int c = g * 256 + w * 64 + l;
    int r = c >> 3, kc = (c & 7) * 8;
    gload16(Q + ((size_t)(b * 1024 + q0 + r)) * QSZ + h * 64 + kc,
            (char*)Qs + (size_t)(g * 256 + w * 64) * 16);
  }

  for (int t = (q0 == 0) ? 1 : 0; t < 2; ++t) {
    int kb = q0 - 128 + t * 128;
#pragma unroll
    for (int g = 0; g < 4; ++g) {
      int c = g * 256 + w * 64 + l;
      int r = c >> 3, kc = (c & 7) * 8;
      gload16(Kg + ((size_t)(b * 1024 + kb + r)) * 512 + kvh * 64 + kc,
              (char*)Ks + (size_t)(g * 256 + w * 64) * 16);
      int rv = c >> 4, kv = (c & 15) * 8;
      gload16(VT + ((size_t)(b * 8 + kvh) * 64 + rv) * 1024 + kb + kv,
              (char*)Vs + (size_t)(g * 256 + w * 64) * 16);
    }
    __syncthreads();

    // S = Q K^T (scale pre-folded into Q)
    f32x4 sacc[2][8] = {};
#pragma unroll
    for (int kk = 0; kk < 2; ++kk) {
      bf16x8 qf[2], kf[8];
#pragma unroll
      for (int mi = 0; mi < 2; ++mi)
        qf[mi] = *reinterpret_cast<const bf16x8*>(&Qs[(w * 32 + mi * 16 + lm) * 64 + kk * 32 + lg * 8]);
#pragma unroll
      for (int ni = 0; ni < 8; ++ni)
        kf[ni] = *reinterpret_cast<const bf16x8*>(&Ks[(ni * 16 + lm) * 64 + kk * 32 + lg * 8]);
#pragma unroll
      for (int mi = 0; mi < 2; ++mi)
#pragma unroll
        for (int ni = 0; ni < 8; ++ni)
          sacc[mi][ni] = __builtin_amdgcn_mfma_f32_16x16x32_bf16(qf[mi], kf[ni], sacc[mi][ni], 0, 0, 0);
    }

    // mask + online softmax (row = lg*4+j within 16-lane group; reduce over lm lanes)
#pragma unroll
    for (int mi = 0; mi < 2; ++mi)
#pragma unroll
      for (int j = 0; j < 4; ++j) {
        int qi = q0 + w * 32 + mi * 16 + lg * 4 + j;
        float mx = -1e30f;
#pragma unroll
        for (int ni = 0; ni < 8; ++ni) {
          int kg = kb + ni * 16 + lm;
          float v = sacc[mi][ni][j];
          v = (kg <= qi && kg >= qi - 127) ? v : -1e30f;
          sacc[mi][ni][j] = v;
          mx = fmaxf(mx, v);
        }
#pragma unroll
        for (int d = 1; d < 16; d <<= 1) mx = fmaxf(mx, __shfl_xor(mx, d, 64));
        float mnew = fmaxf(mrun[mi][j], mx);
        float sum = 0.f;
#pragma unroll
        for (int ni = 0; ni < 8; ++ni) {
          float p = __expf(sacc[mi][ni][j] - mnew);  // masked: exp(-1e30 - m) -> 0
          sacc[mi][ni][j] = p;
          sum += p;
        }
#pragma unroll
        for (int d = 1; d < 16; d <<= 1) sum += __shfl_xor(sum, d, 64);
        float alpha = __expf(mrun[mi][j] - mnew);
        lrun[mi][j] = lrun[mi][j] * alpha + sum;
        mrun[mi][j] = mnew;
#pragma unroll
        for (int ni = 0; ni < 4; ++ni) oacc[mi][ni][j] *= alpha;
#pragma unroll
        for (int ni = 0; ni < 8; ++ni)
          Ps[w][(mi * 16 + lg * 4 + j) * 128 + ni * 16 + lm] = __float2bfloat16(sacc[mi][ni][j]);
      }

    // O += P V   (P from per-wave LDS as A-operand; V^T rows as B-operand)
#pragma unroll
    for (int ks = 0; ks < 4; ++ks) {
      bf16x8 pf[2], vf[4];
#pragma unroll
      for (int mi = 0; mi < 2; ++mi)
        pf[mi] = *reinterpret_cast<const bf16x8*>(&Ps[w][(mi * 16 + lm) * 128 + ks * 32 + lg * 8]);
#pragma unroll
      for (int ni = 0; ni < 4; ++ni)
        vf[ni] = *reinterpret_cast<const bf16x8*>(&Vs[(ni * 16 + lm) * 128 + ks * 32 + lg * 8]);
#pragma unroll
      for (int mi = 0; mi < 2; ++mi)
#pragma unroll
        for (int ni = 0; ni < 4; ++ni)
          oacc[mi][ni] = __builtin_amdgcn_mfma_f32_16x16x32_bf16(pf[mi], vf[ni], oacc[mi][ni], 0, 0, 0);
    }
    __syncthreads();
  }

#pragma unroll
  for (int mi = 0; mi < 2; ++mi)
#pragma unroll
    for (int ni = 0; ni < 4; ++ni)
#pragma unroll
      for (int j = 0; j < 4; ++j) {
        int tok = b * 1024 + q0 + w * 32 + mi * 16 + lg * 4 + j;
        Og[(size_t)tok * QSZ + h * 64 + ni * 16 + lm] =
            __float2bfloat16(oacc[mi][ni][j] / lrun[mi][j]);
      }
}

extern "C" void kernel_launch(void* const* d_in, const int* in_sizes, int n_in,
                              void* d_out, int out_size, void* d_ws, size_t ws_size,
                              hipStream_t stream) {
  const int*   positions = (const int*)d_in[0];
  const float* hidden    = (const float*)d_in[1];
  const float* w_qkv     = (const float*)d_in[2];
  const float* w_o       = (const float*)d_in[3];
  const float* sinks     = (const float*)d_in[4];
  float* out = (float*)d_out;

  char* ws = (char*)d_ws;
  bf16*  hid_b = (bf16*)(ws + 0);            // 2048x2880 bf16      = 11,796,480
  bf16*  wqkvT = (bf16*)(ws + 11796480);     // 5120x2880 bf16      = 29,491,200
  bf16*  woT   = (bf16*)(ws + 41287680);     // 2880x4096 bf16      = 23,592,960
  float* qkv   = (float*)(ws + 64880640);    // 2048x5120 f32       = 41,943,040
  bf16*  qb    = (bf16*)(ws + 106823680);    // 2048x4096 bf16      = 16,777,216
  bf16*  kb    = (bf16*)(ws + 123600896);    // 2048x512 bf16       =  2,097,152
  bf16*  vT    = (bf16*)(ws + 125698048);    // 16x64x1024 bf16     =  2,097,152
  bf16*  attnb = (bf16*)(ws + 127795200);    // 2048x4096 bf16      = 16,777,216

  // 1. conversions
  cvt_f32_bf16_k<<<(NTOK * HIDDEN / 4 + 255) / 256, 256, 0, stream>>>(hidden, hid_b, NTOK * HIDDEN / 4);
  transpose_cvt_k<<<dim3(QKVN / 32, HIDDEN / 32), dim3(32, 8), 0, stream>>>(w_qkv, wqkvT, HIDDEN, QKVN);
  transpose_cvt_k<<<dim3(HIDDEN / 32, QSZ / 32), dim3(32, 8), 0, stream>>>(w_o, woT, QSZ, HIDDEN);
  // 2. QKV projection: [2048,2880] x [2880,5120] -> [2048,5120] f32
  gemm_bt_k<<<(NTOK / 128) * (QKVN / 128), 256, 0, stream>>>(hid_b, wqkvT, qkv, NTOK, QKVN, HIDDEN, QKVN / 128);
  // 3. RoPE + layout
  rope_k<<<NTOK, 256, 0, stream>>>(qkv, positions, qb, kb, vT);
  // 4. attention
  attn_k<<<2 * NH * (SEQ / 128), 256, 0, stream>>>(qb, kb, vT, sinks, attnb);
  // 5. output projection: [2048,4096] x [4096,2880] -> [2048,2880] f32 (N ragged -> 23 tiles)
  gemm_bt_k<<<(NTOK / 128) * 23, 256, 0, stream>>>(attnb, woT, out, NTOK, HIDDEN, QSZ, 23);
}

// Round 2
// 324.146 us; speedup vs baseline: 1.0036x; 1.0036x over previous
//
#include <hip/hip_runtime.h>
#include <hip/hip_bf16.h>
#include <stdint.h>

typedef __hip_bfloat16 bf16;
typedef short bf16x8 __attribute__((ext_vector_type(8)));
typedef float f32x4 __attribute__((ext_vector_type(4)));

#define NTOK 2048
#define HIDDEN 2880
#define QKVN 5120
#define QSZ 4096
#define NH 64
#define NKV 8
#define HD 64
#define SEQ 1024

__device__ __forceinline__ void gload16(const void* g, void* l) {
  __builtin_amdgcn_global_load_lds(
      (const __attribute__((address_space(1))) uint32_t*)g,
      (__attribute__((address_space(3))) uint32_t*)l, 16, 0, 0);
}

// ---------------- fp32 -> bf16 elementwise ----------------
__global__ __launch_bounds__(256) void cvt_f32_bf16_k(const float* __restrict__ src,
                                                      bf16* __restrict__ dst, int n4) {
  int i = blockIdx.x * 256 + threadIdx.x;
  if (i >= n4) return;
  const float4 v = reinterpret_cast<const float4*>(src)[i];
  bf16 o[4] = {__float2bfloat16(v.x), __float2bfloat16(v.y),
               __float2bfloat16(v.z), __float2bfloat16(v.w)};
  reinterpret_cast<uint2*>(dst)[i] = *reinterpret_cast<const uint2*>(o);
}

// ---------------- src[R][C] f32 -> dst[C][R] bf16 (tiled transpose) ----------------
__global__ __launch_bounds__(256) void transpose_cvt_k(const float* __restrict__ src,
                                                       bf16* __restrict__ dst, int R, int C) {
  __shared__ float t[32][33];
  int c0 = blockIdx.x * 32, r0 = blockIdx.y * 32;
  int tx = threadIdx.x, ty = threadIdx.y;
#pragma unroll
  for (int i = 0; i < 4; ++i)
    t[ty + i * 8][tx] = src[(size_t)(r0 + ty + i * 8) * C + c0 + tx];
  __syncthreads();
#pragma unroll
  for (int i = 0; i < 4; ++i)
    dst[(size_t)(c0 + ty + i * 8) * R + r0 + tx] = __float2bfloat16(t[tx][ty + i * 8]);
}

// ---------------- bf16 GEMM: A[M][K] * BT[N][K]^T -> C[M][N] fp32 ----------------
// 128x128 tile, BK=64, 4 waves (2x2 of 64x64), global_load_lds w=16,
// DOUBLE-BUFFERED LDS: stage(t+1) issued before compute(t), one barrier/K-step.
__global__ __launch_bounds__(256) void gemm_bt_k(const bf16* __restrict__ A,
                                                 const bf16* __restrict__ BT,
                                                 float* __restrict__ C,
                                                 int M, int N, int K, int nbn) {
  __shared__ __align__(16) bf16 As[2][128 * 64];
  __shared__ __align__(16) bf16 Bs[2][128 * 64];
  int bm = blockIdx.x / nbn, bn = blockIdx.x % nbn;
  int m0 = bm * 128, n0 = bn * 128;
  int tid = threadIdx.x, w = tid >> 6, l = tid & 63, lg = l >> 4, lm = l & 15;
  int wm = (w >> 1) * 64, wn = (w & 1) * 64;

  // precomputed per-lane staging addresses
  int c = w * 64 + l;
  int r = c >> 3, kc = (c & 7) * 8;        // row within 32-row group, k-offset
  f32x4 acc[4][4] = {};

  auto STAGE = [&](int k0, int buf) {
#pragma unroll
    for (int g = 0; g < 4; ++g) {
      int rr = g * 32 + r;
      int ar = m0 + rr; if (ar > M - 1) ar = M - 1;
      int br = n0 + rr; if (br > N - 1) br = N - 1;
      gload16(A + (size_t)ar * K + k0 + kc, (char*)As[buf] + (size_t)(g * 256 + w * 64) * 16);
      gload16(BT + (size_t)br * K + k0 + kc, (char*)Bs[buf] + (size_t)(g * 256 + w * 64) * 16);
    }
  };

  int nk = K >> 6;
  STAGE(0, 0);
  __syncthreads();               // drains vmcnt(0): buf0 ready
  int cur = 0;
  for (int t = 0; t < nk; ++t) {
    if (t + 1 < nk) STAGE((t + 1) << 6, cur ^ 1);  // prefetch in flight across compute
#pragma unroll
    for (int kk = 0; kk < 2; ++kk) {
      bf16x8 af[4], bfv[4];
#pragma unroll
      for (int mi = 0; mi < 4; ++mi)
        af[mi] = *reinterpret_cast<const bf16x8*>(&As[cur][(wm + mi * 16 + lm) * 64 + kk * 32 + lg * 8]);
#pragma unroll
      for (int ni = 0; ni < 4; ++ni)
        bfv[ni] = *reinterpret_cast<const bf16x8*>(&Bs[cur][(wn + ni * 16 + lm) * 64 + kk * 32 + lg * 8]);
#pragma unroll
      for (int mi = 0; mi < 4; ++mi)
#pragma unroll
        for (int ni = 0; ni < 4; ++ni)
          acc[mi][ni] = __builtin_amdgcn_mfma_f32_16x16x32_bf16(af[mi], bfv[ni], acc[mi][ni], 0, 0, 0);
    }
    __syncthreads();             // drains vmcnt(0): next buffer ready, cur reads done
    cur ^= 1;
  }
#pragma unroll
  for (int mi = 0; mi < 4; ++mi)
#pragma unroll
    for (int ni = 0; ni < 4; ++ni) {
      int col = n0 + wn + ni * 16 + lm;
      if (col >= N) continue;
      int row = m0 + wm + mi * 16 + lg * 4;
#pragma unroll
      for (int j = 0; j < 4; ++j)
        if (row + j < M) C[(size_t)(row + j) * N + col] = acc[mi][ni][j];
    }
}

// ---------------- RoPE + layout: qkv f32 -> q(scaled) bf16, k bf16, v^T bf16 ----------------
__global__ __launch_bounds__(256) void rope_k(const float* __restrict__ qkv,
                                              const int* __restrict__ positions,
                                              bf16* __restrict__ qo,   // [2048][4096]
                                              bf16* __restrict__ ko,   // [2048][512]
                                              bf16* __restrict__ vT) { // [(b*8+kvh)*64+d][1024]
  __shared__ float cs[32], sn[32];
  int t = blockIdx.x;
  int tid = threadIdx.x;
  if (tid < 32) {
    float inv = __expf(-(float)tid * (logf(150000.0f) / 32.0f));
    float a = (float)positions[t] * inv;
    cs[tid] = cosf(a);
    sn[tid] = sinf(a);
  }
  __syncthreads();
  const float* row = qkv + (size_t)t * QKVN;
#pragma unroll
  for (int p = tid; p < NH * 32; p += 256) {
    int h = p >> 5, d = p & 31;
    float x1 = row[h * 64 + d], x2 = row[h * 64 + d + 32];
    qo[(size_t)t * QSZ + h * 64 + d]      = __float2bfloat16((x1 * cs[d] - x2 * sn[d]) * 0.125f);
    qo[(size_t)t * QSZ + h * 64 + d + 32] = __float2bfloat16((x2 * cs[d] + x1 * sn[d]) * 0.125f);
  }
  {
    int p = tid;  // 8 kv heads * 32 = 256 exactly
    int kvh = p >> 5, d = p & 31;
    float x1 = row[QSZ + kvh * 64 + d], x2 = row[QSZ + kvh * 64 + d + 32];
    ko[(size_t)t * 512 + kvh * 64 + d]      = __float2bfloat16(x1 * cs[d] - x2 * sn[d]);
    ko[(size_t)t * 512 + kvh * 64 + d + 32] = __float2bfloat16(x2 * cs[d] + x1 * sn[d]);
  }
  int b = t >> 10, s = t & 1023;
#pragma unroll
  for (int p = tid; p < 512; p += 256) {
    int kvh = p >> 6, d = p & 63;
    vT[((size_t)(b * 8 + kvh) * 64 + d) * 1024 + s] = __float2bfloat16(row[4608 + kvh * 64 + d]);
  }
}

// ---------------- flash attention, sliding window 128, sinks ----------------
__global__ __launch_bounds__(256) void attn_k(const bf16* __restrict__ Q,
                                              const bf16* __restrict__ Kg,
                                              const bf16* __restrict__ VT,
                                              const float* __restrict__ sinks,
                                              bf16* __restrict__ Og) {
  __shared__ __align__(16) bf16 Qs[128 * 64];
  __shared__ __align__(16) bf16 Ks[128 * 64];
  __shared__ __align__(16) bf16 Vs[64 * 128];
  __shared__ __align__(16) bf16 Ps[4][32 * 128];
  int bid = blockIdx.x;
  int b = bid >> 9, rest = bid & 511, h = rest >> 3, qt = rest & 7;
  int q0 = qt * 128, kvh = h >> 3;
  int tid = threadIdx.x, w = tid >> 6, l = tid & 63, lg = l >> 4, lm = l & 15;

  float mrun[2][4], lrun[2][4];
  float ls = __logf(sinks[h]);  // sink folded exactly into online-softmax init
#pragma unroll
  for (int mi = 0; mi < 2; ++mi)
#pragma unroll
    for (int j = 0; j < 4; ++j) { mrun[mi][j] = ls; lrun[mi][j] = 1.0f; }
  f32x4 oacc[2][4] = {};

#pragma unroll
  for (int g = 0; g < 4; ++g) {
    int c = g * 256 + w * 64 + l;
    int r = c >> 3, kc = (c & 7) * 8;
    gload16(Q + ((size_t)(b * 1024 + q0 + r)) * QSZ + h * 64 + kc,
            (char*)Qs + (size_t)(g * 256 + w * 64) * 16);
  }

  for (int t = (q0 == 0) ? 1 : 0; t < 2; ++t) {
    int kb = q0 - 128 + t * 128;
#pragma unroll
    for (int g = 0; g < 4; ++g) {
      int c = g * 256 + w * 64 + l;
      int r = c >> 3, kc = (c & 7) * 8;
      gload16(Kg + ((size_t)(b * 1024 + kb + r)) * 512 + kvh * 64 + kc,
              (char*)Ks + (size_t)(g * 256 + w * 64) * 16);
      int rv = c >> 4, kv = (c & 15) * 8;
      gload16(VT + ((size_t)(b * 8 + kvh) * 64 + rv) * 1024 + kb + kv,
              (char*)Vs + (size_t)(g * 256 + w * 64) * 16);
    }
    __syncthreads();

    // S = Q K^T (scale pre-folded into Q)
    f32x4 sacc[2][8] = {};
#pragma unroll
    for (int kk = 0; kk < 2; ++kk) {
      bf16x8 qf[2], kf[8];
#pragma unroll
      for (int mi = 0; mi < 2; ++mi)
        qf[mi] = *reinterpret_cast<const bf16x8*>(&Qs[(w * 32 + mi * 16 + lm) * 64 + kk * 32 + lg * 8]);
#pragma unroll
      for (int ni = 0; ni < 8; ++ni)
        kf[ni] = *reinterpret_cast<const bf16x8*>(&Ks[(ni * 16 + lm) * 64 + kk * 32 + lg * 8]);
#pragma unroll
      for (int mi = 0; mi < 2; ++mi)
#pragma unroll
        for (int ni = 0; ni < 8; ++ni)
          sacc[mi][ni] = __builtin_amdgcn_mfma_f32_16x16x32_bf16(qf[mi], kf[ni], sacc[mi][ni], 0, 0, 0);
    }

    // mask + online softmax
#pragma unroll
    for (int mi = 0; mi < 2; ++mi)
#pragma unroll
      for (int j = 0; j < 4; ++j) {
        int qi = q0 + w * 32 + mi * 16 + lg * 4 + j;
        float mx = -1e30f;
#pragma unroll
        for (int ni = 0; ni < 8; ++ni) {
          int kg = kb + ni * 16 + lm;
          float v = sacc[mi][ni][j];
          v = (kg <= qi && kg >= qi - 127) ? v : -1e30f;
          sacc[mi][ni][j] = v;
          mx = fmaxf(mx, v);
        }
#pragma unroll
        for (int d = 1; d < 16; d <<= 1) mx = fmaxf(mx, __shfl_xor(mx, d, 64));
        float mnew = fmaxf(mrun[mi][j], mx);
        float sum = 0.f;
#pragma unroll
        for (int ni = 0; ni < 8; ++ni) {
          float p = __expf(sacc[mi][ni][j] - mnew);
          sacc[mi][ni][j] = p;
          sum += p;
        }
#pragma unroll
        for (int d = 1; d < 16; d <<= 1) sum += __shfl_xor(sum, d, 64);
        float alpha = __expf(mrun[mi][j] - mnew);
        lrun[mi][j] = lrun[mi][j] * alpha + sum;
        mrun[mi][j] = mnew;
#pragma unroll
        for (int ni = 0; ni < 4; ++ni) oacc[mi][ni][j] *= alpha;
#pragma unroll
        for (int ni = 0; ni < 8; ++ni)
          Ps[w][(mi * 16 + lg * 4 + j) * 128 + ni * 16 + lm] = __float2bfloat16(sacc[mi][ni][j]);
      }

    // O += P V
#pragma unroll
    for (int ks = 0; ks < 4; ++ks) {
      bf16x8 pf[2], vf[4];
#pragma unroll
      for (int mi = 0; mi < 2; ++mi)
        pf[mi] = *reinterpret_cast<const bf16x8*>(&Ps[w][(mi * 16 + lm) * 128 + ks * 32 + lg * 8]);
#pragma unroll
      for (int ni = 0; ni < 4; ++ni)
        vf[ni] = *reinterpret_cast<const bf16x8*>(&Vs[(ni * 16 + lm) * 128 + ks * 32 + lg * 8]);
#pragma unroll
      for (int mi = 0; mi < 2; ++mi)
#pragma unroll
        for (int ni = 0; ni < 4; ++ni)
          oacc[mi][ni] = __builtin_amdgcn_mfma_f32_16x16x32_bf16(pf[mi], vf[ni], oacc[mi][ni], 0, 0, 0);
    }
    __syncthreads();
  }

#pragma unroll
  for (int mi = 0; mi < 2; ++mi)
#pragma unroll
    for (int ni = 0; ni < 4; ++ni)
#pragma unroll
      for (int j = 0; j < 4; ++j) {
        int tok = b * 1024 + q0 + w * 32 + mi * 16 + lg * 4 + j;
        Og[(size_t)tok * QSZ + h * 64 + ni * 16 + lm] =
            __float2bfloat16(oacc[mi][ni][j] / lrun[mi][j]);
      }
}

extern "C" void kernel_launch(void* const* d_in, const int* in_sizes, int n_in,
                              void* d_out, int out_size, void* d_ws, size_t ws_size,
                              hipStream_t stream) {
  const int*   positions = (const int*)d_in[0];
  const float* hidden    = (const float*)d_in[1];
  const float* w_qkv     = (const float*)d_in[2];
  const float* w_o       = (const float*)d_in[3];
  const float* sinks     = (const float*)d_in[4];
  float* out = (float*)d_out;

  char* ws = (char*)d_ws;
  bf16*  hid_b = (bf16*)(ws + 0);            // 2048x2880 bf16      = 11,796,480
  bf16*  wqkvT = (bf16*)(ws + 11796480);     // 5120x2880 bf16      = 29,491,200
  bf16*  woT   = (bf16*)(ws + 41287680);     // 2880x4096 bf16      = 23,592,960
  float* qkv   = (float*)(ws + 64880640);    // 2048x5120 f32       = 41,943,040
  bf16*  qb    = (bf16*)(ws + 106823680);    // 2048x4096 bf16      = 16,777,216
  bf16*  kb    = (bf16*)(ws + 123600896);    // 2048x512 bf16       =  2,097,152
  bf16*  vT    = (bf16*)(ws + 125698048);    // 16x64x1024 bf16     =  2,097,152
  bf16*  attnb = (bf16*)(ws + 127795200);    // 2048x4096 bf16      = 16,777,216

  // 1. conversions
  cvt_f32_bf16_k<<<(NTOK * HIDDEN / 4 + 255) / 256, 256, 0, stream>>>(hidden, hid_b, NTOK * HIDDEN / 4);
  transpose_cvt_k<<<dim3(QKVN / 32, HIDDEN / 32), dim3(32, 8), 0, stream>>>(w_qkv, wqkvT, HIDDEN, QKVN);
  transpose_cvt_k<<<dim3(HIDDEN / 32, QSZ / 32), dim3(32, 8), 0, stream>>>(w_o, woT, QSZ, HIDDEN);
  // 2. QKV projection: [2048,2880] x [2880,5120] -> [2048,5120] f32
  gemm_bt_k<<<(NTOK / 128) * (QKVN / 128), 256, 0, stream>>>(hid_b, wqkvT, qkv, NTOK, QKVN, HIDDEN, QKVN / 128);
  // 3. RoPE + layout
  rope_k<<<NTOK, 256, 0, stream>>>(qkv, positions, qb, kb, vT);
  // 4. attention
  attn_k<<<2 * NH * (SEQ / 128), 256, 0, stream>>>(qb, kb, vT, sinks, attnb);
  // 5. output projection: [2048,4096] x [4096,2880] -> [2048,2880] f32 (N ragged -> 23 tiles)
  gemm_bt_k<<<(NTOK / 128) * 23, 256, 0, stream>>>(attnb, woT, out, NTOK, HIDDEN, QSZ, 23);
}

// Round 3
// 265.981 us; speedup vs baseline: 1.2230x; 1.2187x over previous
//
#include <hip/hip_runtime.h>
#include <hip/hip_bf16.h>
#include <stdint.h>

typedef __hip_bfloat16 bf16;
typedef short bf16x8 __attribute__((ext_vector_type(8)));
typedef float f32x4 __attribute__((ext_vector_type(4)));

#define NTOK 2048
#define HIDDEN 2880
#define KPAD 2944
#define QKVN 5120
#define QSZ 4096
#define NH 64
#define NKV 8
#define HD 64
#define SEQ 1024

__device__ __forceinline__ void gload16(const void* g, void* l) {
  __builtin_amdgcn_global_load_lds(
      (const __attribute__((address_space(1))) uint32_t*)g,
      (__attribute__((address_space(3))) uint32_t*)l, 16, 0, 0);
}

// ---------------- fp32 -> bf16 with zero-padded K (row stride colsPad) ----------------
__global__ __launch_bounds__(256) void cvt_pad_k(const float* __restrict__ src,
                                                 bf16* __restrict__ dst,
                                                 int rows, int cols, int colsPad) {
  int gpr = colsPad >> 3;
  int i = blockIdx.x * 256 + threadIdx.x;
  if (i >= rows * gpr) return;
  int r = i / gpr, c8 = (i - r * gpr) << 3;
  bf16 o[8];
  if (c8 < cols) {
    const float4 v0 = *(const float4*)(src + (size_t)r * cols + c8);
    const float4 v1 = *(const float4*)(src + (size_t)r * cols + c8 + 4);
    o[0] = __float2bfloat16(v0.x); o[1] = __float2bfloat16(v0.y);
    o[2] = __float2bfloat16(v0.z); o[3] = __float2bfloat16(v0.w);
    o[4] = __float2bfloat16(v1.x); o[5] = __float2bfloat16(v1.y);
    o[6] = __float2bfloat16(v1.z); o[7] = __float2bfloat16(v1.w);
  } else {
#pragma unroll
    for (int j = 0; j < 8; ++j) o[j] = __float2bfloat16(0.f);
  }
  *(uint4*)(dst + (size_t)r * colsPad + c8) = *(const uint4*)o;
}

// ---------------- src[R][C] f32 -> dst[C][dstLd] bf16 (tiled transpose, zero pad r>=R) ----
__global__ __launch_bounds__(256) void transpose_cvt_k(const float* __restrict__ src,
                                                       bf16* __restrict__ dst,
                                                       int R, int C, int dstLd) {
  __shared__ float t[32][33];
  int c0 = blockIdx.x * 32, r0 = blockIdx.y * 32;
  int tx = threadIdx.x, ty = threadIdx.y;
#pragma unroll
  for (int i = 0; i < 4; ++i) {
    int r = r0 + ty + i * 8;
    t[ty + i * 8][tx] = (r < R) ? src[(size_t)r * C + c0 + tx] : 0.f;
  }
  __syncthreads();
#pragma unroll
  for (int i = 0; i < 4; ++i)
    dst[(size_t)(c0 + ty + i * 8) * dstLd + r0 + tx] = __float2bfloat16(t[tx][ty + i * 8]);
}

// =====================================================================================
// 256x256 8-phase bf16 GEMM (T2 swizzle + T3/T4 counted vmcnt + T5 setprio)
// A[2048][ldk] * BT[N][ldk]^T -> C[2048][N] (f32 or bf16). Optional 2-way K-split.
// 8 waves (2M x 4N), BK=64, LDS = 8 half-slots x 16KB (A0,A1,B0,B1 per K-tile parity).
// Swizzle: LDS[row][g] holds global granule g^(row&7) (pre-swizzled source, rule 21).
// =====================================================================================
#define LDB(par) { \
  const char* _bb = lds + (((par)*4 + 2 + (wn>>1)) << 14); \
  _Pragma("unroll") \
  for (int _n = 0; _n < 4; ++_n) { \
    int _r = ((wn&1)<<6) + _n*16 + lm; \
    _Pragma("unroll") \
    for (int _kk = 0; _kk < 2; ++_kk) \
      bq[_n][_kk] = *(const bf16x8*)(_bb + _r*128 + (((_kk*4 + lg) ^ (_r & 7)) << 4)); } }

#define LDA(par, qc) { \
  const char* _ab = lds + (((par)*4 + wm) << 14); \
  _Pragma("unroll") \
  for (int _f = 0; _f < 2; ++_f) { \
    int _r = (qc)*32 + _f*16 + lm; \
    _Pragma("unroll") \
    for (int _kk = 0; _kk < 2; ++_kk) \
      af[_f][_kk] = *(const bf16x8*)(_ab + _r*128 + (((_kk*4 + lg) ^ (_r & 7)) << 4)); } }

#define MMQ(qc) \
  _Pragma("unroll") \
  for (int _kk = 0; _kk < 2; ++_kk) \
  _Pragma("unroll") \
  for (int _f = 0; _f < 2; ++_f) \
  _Pragma("unroll") \
  for (int _n = 0; _n < 4; ++_n) \
    acc[(qc)*2 + _f][_n] = __builtin_amdgcn_mfma_f32_16x16x32_bf16( \
        af[_f][_kk], bq[_n][_kk], acc[(qc)*2 + _f][_n], 0, 0, 0);

#define PHASE(qc, par, STMT, VMSTMT) { \
  bf16x8 af[2][2]; \
  if ((qc) == 0) { LDB(par); } \
  LDA(par, qc); \
  STMT \
  __builtin_amdgcn_s_barrier(); \
  asm volatile("s_waitcnt lgkmcnt(0)" ::: "memory"); \
  __builtin_amdgcn_sched_barrier(0); \
  __builtin_amdgcn_s_setprio(1); \
  MMQ(qc); \
  __builtin_amdgcn_s_setprio(0); \
  VMSTMT \
  __builtin_amdgcn_s_barrier(); }

template<bool CBF16>
__global__ __launch_bounds__(512, 2) void gemm256_k(
    const bf16* __restrict__ A, const bf16* __restrict__ BT,
    float* __restrict__ C0, float* __restrict__ C1, bf16* __restrict__ Cb,
    int N, int ldk, int nbn, int npair, int ksplit) {
  __shared__ __align__(16) char lds[131072];
  int tid = threadIdx.x;
  int l = tid & 63, lg = l >> 4, lm = l & 15;
  int w = tid >> 6, wm = w >> 2, wn = w & 3;
  int bid = blockIdx.x, kbeg = 0;
  float* C = C0;
  if (ksplit) {
    int half = gridDim.x >> 1;
    if (bid >= half) { bid -= half; kbeg = ksplit; C = C1; }
  }
  int bm = bid / nbn, bn = bid - bm * nbn;
  int m0 = bm << 8, n0 = bn << 8;
  int Bmax = N - 1;
  f32x4 acc[8][4] = {};
  bf16x8 bq[4][2];

  auto STG = [&](int slot, const bf16* mat, int rowBase, int rowMax, int kbase) {
#pragma unroll
    for (int rep = 0; rep < 2; ++rep) {
      int gi = (rep << 9) + tid;
      int row = gi >> 3, g = gi & 7;
      int gr = rowBase + row; if (gr > rowMax) gr = rowMax;
      gload16(mat + (size_t)gr * ldk + kbase + ((g ^ (row & 7)) << 3),
              lds + slot * 16384 + gi * 16);
    }
  };

  // prologue: K-tile0 fully (slots 0-3), K-tile1 B halves (slots 6,7)
  STG(0, A, m0, 2047, kbeg);
  STG(1, A, m0 + 128, 2047, kbeg);
  STG(2, BT, n0, Bmax, kbeg);
  STG(3, BT, n0 + 128, Bmax, kbeg);
  STG(6, BT, n0, Bmax, kbeg + 64);
  STG(7, BT, n0 + 128, Bmax, kbeg + 64);
  asm volatile("s_waitcnt vmcnt(4)" ::: "memory");
  __builtin_amdgcn_s_barrier();

  for (int i = 0; i < npair; ++i) {
    int kt = kbeg + (i << 7);
    bool pf = (i + 1 < npair);
    // K-tile kt (parity 0): mandatory A(kt+64) staging, prefetch B(kt+128)
    PHASE(0, 0, { STG(4, A, m0, 2047, kt + 64); }, ;)
    PHASE(1, 0, { STG(5, A, m0 + 128, 2047, kt + 64); }, ;)
    PHASE(2, 0, { if (pf) STG(2, BT, n0, Bmax, kt + 128); }, ;)
    PHASE(3, 0, { if (pf) STG(3, BT, n0 + 128, Bmax, kt + 128); },
          { if (pf) { asm volatile("s_waitcnt vmcnt(4)" ::: "memory"); }
            else    { asm volatile("s_waitcnt vmcnt(0)" ::: "memory"); } })
    // K-tile kt+64 (parity 1): prefetch A(kt+128), B(kt+192)
    PHASE(0, 1, { if (pf) STG(0, A, m0, 2047, kt + 128); }, ;)
    PHASE(1, 1, { if (pf) STG(1, A, m0 + 128, 2047, kt + 128); }, ;)
    PHASE(2, 1, { if (pf) STG(6, BT, n0, Bmax, kt + 192); }, ;)
    PHASE(3, 1, { if (pf) STG(7, BT, n0 + 128, Bmax, kt + 192); },
          { if (pf) { asm volatile("s_waitcnt vmcnt(4)" ::: "memory"); } })
  }

#pragma unroll
  for (int mf = 0; mf < 8; ++mf)
#pragma unroll
    for (int nf = 0; nf < 4; ++nf) {
      int col = n0 + (wn << 6) + nf * 16 + lm;
      if (col >= N) continue;
      int row = m0 + (wm << 7) + mf * 16 + lg * 4;
      if (CBF16) {
#pragma unroll
        for (int j = 0; j < 4; ++j)
          Cb[(size_t)(row + j) * N + col] = __float2bfloat16(acc[mf][nf][j]);
      } else {
#pragma unroll
        for (int j = 0; j < 4; ++j)
          C[(size_t)(row + j) * N + col] = acc[mf][nf][j];
      }
    }
}

// ---------------- RoPE + layout: qkv bf16 -> q(scaled) bf16, k bf16, v^T bf16 ----------
__global__ __launch_bounds__(256) void rope_k(const bf16* __restrict__ qkv,
                                              const int* __restrict__ positions,
                                              bf16* __restrict__ qo,   // [2048][4096]
                                              bf16* __restrict__ ko,   // [2048][512]
                                              bf16* __restrict__ vT) { // [(b*8+kvh)*64+d][1024]
  __shared__ float cs[32], sn[32];
  int t = blockIdx.x;
  int tid = threadIdx.x;
  if (tid < 32) {
    float inv = __expf(-(float)tid * (logf(150000.0f) / 32.0f));
    float a = (float)positions[t] * inv;
    cs[tid] = cosf(a);
    sn[tid] = sinf(a);
  }
  __syncthreads();
  const bf16* row = qkv + (size_t)t * QKVN;
#pragma unroll
  for (int p = tid; p < NH * 32; p += 256) {
    int h = p >> 5, d = p & 31;
    float x1 = __bfloat162float(row[h * 64 + d]), x2 = __bfloat162float(row[h * 64 + d + 32]);
    qo[(size_t)t * QSZ + h * 64 + d]      = __float2bfloat16((x1 * cs[d] - x2 * sn[d]) * 0.125f);
    qo[(size_t)t * QSZ + h * 64 + d + 32] = __float2bfloat16((x2 * cs[d] + x1 * sn[d]) * 0.125f);
  }
  {
    int p = tid;  // 8 kv heads * 32 = 256 exactly
    int kvh = p >> 5, d = p & 31;
    float x1 = __bfloat162float(row[QSZ + kvh * 64 + d]);
    float x2 = __bfloat162float(row[QSZ + kvh * 64 + d + 32]);
    ko[(size_t)t * 512 + kvh * 64 + d]      = __float2bfloat16(x1 * cs[d] - x2 * sn[d]);
    ko[(size_t)t * 512 + kvh * 64 + d + 32] = __float2bfloat16(x2 * cs[d] + x1 * sn[d]);
  }
  int b = t >> 10, s = t & 1023;
#pragma unroll
  for (int p = tid; p < 512; p += 256) {
    int kvh = p >> 6, d = p & 63;
    vT[((size_t)(b * 8 + kvh) * 64 + d) * 1024 + s] = row[4608 + kvh * 64 + d];
  }
}

// ---------------- flash attention, sliding window 128, sinks ----------------
__global__ __launch_bounds__(256) void attn_k(const bf16* __restrict__ Q,
                                              const bf16* __restrict__ Kg,
                                              const bf16* __restrict__ VT,
                                              const float* __restrict__ sinks,
                                              bf16* __restrict__ Og) {
  __shared__ __align__(16) bf16 Qs[128 * 64];
  __shared__ __align__(16) bf16 Ks[128 * 64];
  __shared__ __align__(16) bf16 Vs[64 * 128];
  __shared__ __align__(16) bf16 Ps[4][32 * 128];
  int bid = blockIdx.x;
  int b = bid >> 9, rest = bid & 511, h = rest >> 3, qt = rest & 7;
  int q0 = qt * 128, kvh = h >> 3;
  int tid = threadIdx.x, w = tid >> 6, l = tid & 63, lg = l >> 4, lm = l & 15;

  float mrun[2][4], lrun[2][4];
  float ls = __logf(sinks[h]);  // sink folded exactly into online-softmax init
#pragma unroll
  for (int mi = 0; mi < 2; ++mi)
#pragma unroll
    for (int j = 0; j < 4; ++j) { mrun[mi][j] = ls; lrun[mi][j] = 1.0f; }
  f32x4 oacc[2][4] = {};

#pragma unroll
  for (int g = 0; g < 4; ++g) {
    int c = g * 256 + w * 64 + l;
    int r = c >> 3, kc = (c & 7) * 8;
    gload16(Q + ((size_t)(b * 1024 + q0 + r)) * QSZ + h * 64 + kc,
            (char*)Qs + (size_t)(g * 256 + w * 64) * 16);
  }

  for (int t = (q0 == 0) ? 1 : 0; t < 2; ++t) {
    int kb = q0 - 128 + t * 128;
#pragma unroll
    for (int g = 0; g < 4; ++g) {
      int c = g * 256 + w * 64 + l;
      int r = c >> 3, kc = (c & 7) * 8;
      gload16(Kg + ((size_t)(b * 1024 + kb + r)) * 512 + kvh * 64 + kc,
              (char*)Ks + (size_t)(g * 256 + w * 64) * 16);
      int rv = c >> 4, kv = (c & 15) * 8;
      gload16(VT + ((size_t)(b * 8 + kvh) * 64 + rv) * 1024 + kb + kv,
              (char*)Vs + (size_t)(g * 256 + w * 64) * 16);
    }
    __syncthreads();

    f32x4 sacc[2][8] = {};
#pragma unroll
    for (int kk = 0; kk < 2; ++kk) {
      bf16x8 qf[2], kf[8];
#pragma unroll
      for (int mi = 0; mi < 2; ++mi)
        qf[mi] = *reinterpret_cast<const bf16x8*>(&Qs[(w * 32 + mi * 16 + lm) * 64 + kk * 32 + lg * 8]);
#pragma unroll
      for (int ni = 0; ni < 8; ++ni)
        kf[ni] = *reinterpret_cast<const bf16x8*>(&Ks[(ni * 16 + lm) * 64 + kk * 32 + lg * 8]);
#pragma unroll
      for (int mi = 0; mi < 2; ++mi)
#pragma unroll
        for (int ni = 0; ni < 8; ++ni)
          sacc[mi][ni] = __builtin_amdgcn_mfma_f32_16x16x32_bf16(qf[mi], kf[ni], sacc[mi][ni], 0, 0, 0);
    }

#pragma unroll
    for (int mi = 0; mi < 2; ++mi)
#pragma unroll
      for (int j = 0; j < 4; ++j) {
        int qi = q0 + w * 32 + mi * 16 + lg * 4 + j;
        float mx = -1e30f;
#pragma unroll
        for (int ni = 0; ni < 8; ++ni) {
          int kg = kb + ni * 16 + lm;
          float v = sacc[mi][ni][j];
          v = (kg <= qi && kg >= qi - 127) ? v : -1e30f;
          sacc[mi][ni][j] = v;
          mx = fmaxf(mx, v);
        }
#pragma unroll
        for (int d = 1; d < 16; d <<= 1) mx = fmaxf(mx, __shfl_xor(mx, d, 64));
        float mnew = fmaxf(mrun[mi][j], mx);
        float sum = 0.f;
#pragma unroll
        for (int ni = 0; ni < 8; ++ni) {
          float p = __expf(sacc[mi][ni][j] - mnew);
          sacc[mi][ni][j] = p;
          sum += p;
        }
#pragma unroll
        for (int d = 1; d < 16; d <<= 1) sum += __shfl_xor(sum, d, 64);
        float alpha = __expf(mrun[mi][j] - mnew);
        lrun[mi][j] = lrun[mi][j] * alpha + sum;
        mrun[mi][j] = mnew;
#pragma unroll
        for (int ni = 0; ni < 4; ++ni) oacc[mi][ni][j] *= alpha;
#pragma unroll
        for (int ni = 0; ni < 8; ++ni)
          Ps[w][(mi * 16 + lg * 4 + j) * 128 + ni * 16 + lm] = __float2bfloat16(sacc[mi][ni][j]);
      }

#pragma unroll
    for (int ks = 0; ks < 4; ++ks) {
      bf16x8 pf[2], vf[4];
#pragma unroll
      for (int mi = 0; mi < 2; ++mi)
        pf[mi] = *reinterpret_cast<const bf16x8*>(&Ps[w][(mi * 16 + lm) * 128 + ks * 32 + lg * 8]);
#pragma unroll
      for (int ni = 0; ni < 4; ++ni)
        vf[ni] = *reinterpret_cast<const bf16x8*>(&Vs[(ni * 16 + lm) * 128 + ks * 32 + lg * 8]);
#pragma unroll
      for (int mi = 0; mi < 2; ++mi)
#pragma unroll
        for (int ni = 0; ni < 4; ++ni)
          oacc[mi][ni] = __builtin_amdgcn_mfma_f32_16x16x32_bf16(pf[mi], vf[ni], oacc[mi][ni], 0, 0, 0);
    }
    __syncthreads();
  }

#pragma unroll
  for (int mi = 0; mi < 2; ++mi)
#pragma unroll
    for (int ni = 0; ni < 4; ++ni)
#pragma unroll
      for (int j = 0; j < 4; ++j) {
        int tok = b * 1024 + q0 + w * 32 + mi * 16 + lg * 4 + j;
        Og[(size_t)tok * QSZ + h * 64 + ni * 16 + lm] =
            __float2bfloat16(oacc[mi][ni][j] / lrun[mi][j]);
      }
}

// ---------------- add two f32 partials -> f32 out ----------------
__global__ __launch_bounds__(256) void add2_k(const float* __restrict__ a,
                                              const float* __restrict__ b,
                                              float* __restrict__ o, int n4) {
  int i = blockIdx.x * 256 + threadIdx.x;
  if (i >= n4) return;
  float4 x = reinterpret_cast<const float4*>(a)[i];
  float4 y = reinterpret_cast<const float4*>(b)[i];
  reinterpret_cast<float4*>(o)[i] = make_float4(x.x + y.x, x.y + y.y, x.z + y.z, x.w + y.w);
}

extern "C" void kernel_launch(void* const* d_in, const int* in_sizes, int n_in,
                              void* d_out, int out_size, void* d_ws, size_t ws_size,
                              hipStream_t stream) {
  const int*   positions = (const int*)d_in[0];
  const float* hidden    = (const float*)d_in[1];
  const float* w_qkv     = (const float*)d_in[2];
  const float* w_o       = (const float*)d_in[3];
  const float* sinks     = (const float*)d_in[4];
  float* out = (float*)d_out;

  char* ws = (char*)d_ws;
  bf16*  wqkvT = (bf16*)(ws + 0);            // [5120][2944]  = 30,146,560 B
  bf16*  woT   = (bf16*)(ws + 30146560);     // [2880][4096]  = 23,592,960
  bf16*  qb    = (bf16*)(ws + 53739520);     // [2048][4096]  = 16,777,216
  bf16*  kb    = (bf16*)(ws + 70516736);     // [2048][512]   =  2,097,152
  bf16*  vT    = (bf16*)(ws + 72613888);     // [16*64][1024] =  2,097,152
  bf16*  attnb = (bf16*)(ws + 74711040);     // [2048][4096]  = 16,777,216
  bf16*  hid_b = (bf16*)(ws + 91488256);     // [2048][2944]  = 12,058,624 (dead after QKV gemm)
  bf16*  qkvb  = (bf16*)(ws + 103546880);    // [2048][5120]  = 20,971,520 (dead after rope)
  float* Cp0   = (float*)(ws + 91488256);    // overlay hid_b/qkvb: [2048][2880] f32
  float* Cp1   = (float*)(ws + 115081216);   // ends 138,674,176

  // 1. conversions (K zero-padded to 2944)
  cvt_pad_k<<<2944, 256, 0, stream>>>(hidden, hid_b, NTOK, HIDDEN, KPAD);
  transpose_cvt_k<<<dim3(QKVN / 32, KPAD / 32), dim3(32, 8), 0, stream>>>(w_qkv, wqkvT, HIDDEN, QKVN, KPAD);
  transpose_cvt_k<<<dim3(HIDDEN / 32, QSZ / 32), dim3(32, 8), 0, stream>>>(w_o, woT, QSZ, HIDDEN, QSZ);
  // 2. QKV projection: [2048,2944] x [2944,5120] -> bf16 [2048,5120]
  gemm256_k<true><<<(NTOK / 256) * (QKVN / 256), 512, 0, stream>>>(
      hid_b, wqkvT, nullptr, nullptr, qkvb, QKVN, KPAD, QKVN / 256, KPAD / 128, 0);
  // 3. RoPE + layout
  rope_k<<<NTOK, 256, 0, stream>>>(qkvb, positions, qb, kb, vT);
  // 4. attention
  attn_k<<<2 * NH * (SEQ / 128), 256, 0, stream>>>(qb, kb, vT, sinks, attnb);
  // 5. output projection with 2-way K-split: [2048,4096] x [4096,2880] -> 2 f32 partials
  gemm256_k<false><<<2 * (NTOK / 256) * 12, 512, 0, stream>>>(
      attnb, woT, Cp0, Cp1, nullptr, HIDDEN, QSZ, 12, 16, 2048);
  // 6. partial sum -> out
  add2_k<<<(NTOK * HIDDEN / 4) / 256, 256, 0, stream>>>(Cp0, Cp1, out, NTOK * HIDDEN / 4);
}

// Round 4
// 243.935 us; speedup vs baseline: 1.3336x; 1.0904x over previous
//
#include <hip/hip_runtime.h>
#include <hip/hip_bf16.h>
#include <stdint.h>

typedef __hip_bfloat16 bf16;
typedef short bf16x8 __attribute__((ext_vector_type(8)));
typedef float f32x4 __attribute__((ext_vector_type(4)));

#define NTOK 2048
#define HIDDEN 2880
#define KPAD 2944
#define QKVN 5120
#define QSZ 4096
#define NH 64
#define NKV 8
#define HD 64
#define SEQ 1024

__device__ __forceinline__ void gload16(const void* g, void* l) {
  __builtin_amdgcn_global_load_lds(
      (const __attribute__((address_space(1))) uint32_t*)g,
      (__attribute__((address_space(3))) uint32_t*)l, 16, 0, 0);
}

// ---------------- sincos table: cosT/sinT[d31][t], t=0..2047 ----------------
__global__ __launch_bounds__(256) void sincos_k(const int* __restrict__ positions,
                                                float* __restrict__ cosT,
                                                float* __restrict__ sinT) {
  int i = blockIdx.x * 256 + threadIdx.x;   // 32*2048 total
  int d = i >> 11, t = i & 2047;
  float inv = powf(150000.0f, -(float)d / 32.0f);
  float a = (float)positions[t] * inv;
  cosT[i] = cosf(a);
  sinT[i] = sinf(a);
}

// ---------------- fp32 -> bf16 with zero-padded K (row stride colsPad) ----------------
__global__ __launch_bounds__(256) void cvt_pad_k(const float* __restrict__ src,
                                                 bf16* __restrict__ dst,
                                                 int rows, int cols, int colsPad) {
  int gpr = colsPad >> 3;
  int i = blockIdx.x * 256 + threadIdx.x;
  if (i >= rows * gpr) return;
  int r = i / gpr, c8 = (i - r * gpr) << 3;
  bf16 o[8];
  if (c8 < cols) {
    const float4 v0 = *(const float4*)(src + (size_t)r * cols + c8);
    const float4 v1 = *(const float4*)(src + (size_t)r * cols + c8 + 4);
    o[0] = __float2bfloat16(v0.x); o[1] = __float2bfloat16(v0.y);
    o[2] = __float2bfloat16(v0.z); o[3] = __float2bfloat16(v0.w);
    o[4] = __float2bfloat16(v1.x); o[5] = __float2bfloat16(v1.y);
    o[6] = __float2bfloat16(v1.z); o[7] = __float2bfloat16(v1.w);
  } else {
#pragma unroll
    for (int j = 0; j < 8; ++j) o[j] = __float2bfloat16(0.f);
  }
  *(uint4*)(dst + (size_t)r * colsPad + c8) = *(const uint4*)o;
}

// ------- src[R][C] f32 -> dst[C][dstLd] bf16, 64x64 tiles, 16B stores, zero pad r>=R ----
__global__ __launch_bounds__(256) void transpose_cvt_k(const float* __restrict__ src,
                                                       bf16* __restrict__ dst,
                                                       int R, int C, int dstLd) {
  __shared__ float t[64][68];          // stride 68: 16B-aligned float4 rows, low conflict
  int c0 = blockIdx.x * 64, r0 = blockIdx.y * 64;
  int tid = threadIdx.x;
  int lr = tid >> 2, lc4 = (tid & 3) << 4;   // load: row lr, 16 cols
  {
    int r = r0 + lr;
    if (r < R) {
      const float* s = src + (size_t)r * C + c0 + lc4;
      *(float4*)&t[lr][lc4 + 0]  = *(const float4*)(s + 0);
      *(float4*)&t[lr][lc4 + 4]  = *(const float4*)(s + 4);
      *(float4*)&t[lr][lc4 + 8]  = *(const float4*)(s + 8);
      *(float4*)&t[lr][lc4 + 12] = *(const float4*)(s + 12);
    } else {
      float4 z = make_float4(0.f, 0.f, 0.f, 0.f);
      *(float4*)&t[lr][lc4 + 0]  = z; *(float4*)&t[lr][lc4 + 4]  = z;
      *(float4*)&t[lr][lc4 + 8]  = z; *(float4*)&t[lr][lc4 + 12] = z;
    }
  }
  __syncthreads();
  // gather: dst row dr = src col; 4 threads x 2 reps cover 64 src rows
  int dr = tid >> 2;
#pragma unroll
  for (int rep = 0; rep < 2; ++rep) {
    int dc0 = (tid & 3) * 16 + rep * 8;
    bf16 o[8];
#pragma unroll
    for (int k = 0; k < 8; ++k) o[k] = __float2bfloat16(t[dc0 + k][dr]);
    *(uint4*)(dst + (size_t)(c0 + dr) * dstLd + r0 + dc0) = *(const uint4*)o;
  }
}

// =====================================================================================
// 256x256 8-phase bf16 GEMM (T2 swizzle + T3/T4 counted vmcnt + T5 setprio)
// EPI=0: C f32 (C0/C1 by ksplit half). EPI=1: C bf16. EPI=2: fused RoPE epilogue.
// =====================================================================================
#define LDB(par) { \
  const char* _bb = lds + (((par)*4 + 2 + (wn>>1)) << 14); \
  _Pragma("unroll") \
  for (int _n = 0; _n < 4; ++_n) { \
    int _r = ((wn&1)<<6) + _n*16 + lm; \
    _Pragma("unroll") \
    for (int _kk = 0; _kk < 2; ++_kk) \
      bq[_n][_kk] = *(const bf16x8*)(_bb + _r*128 + (((_kk*4 + lg) ^ (_r & 7)) << 4)); } }

#define LDA(par, qc) { \
  const char* _ab = lds + (((par)*4 + wm) << 14); \
  _Pragma("unroll") \
  for (int _f = 0; _f < 2; ++_f) { \
    int _r = (qc)*32 + _f*16 + lm; \
    _Pragma("unroll") \
    for (int _kk = 0; _kk < 2; ++_kk) \
      af[_f][_kk] = *(const bf16x8*)(_ab + _r*128 + (((_kk*4 + lg) ^ (_r & 7)) << 4)); } }

#define MMQ(qc) \
  _Pragma("unroll") \
  for (int _kk = 0; _kk < 2; ++_kk) \
  _Pragma("unroll") \
  for (int _f = 0; _f < 2; ++_f) \
  _Pragma("unroll") \
  for (int _n = 0; _n < 4; ++_n) \
    acc[(qc)*2 + _f][_n] = __builtin_amdgcn_mfma_f32_16x16x32_bf16( \
        af[_f][_kk], bq[_n][_kk], acc[(qc)*2 + _f][_n], 0, 0, 0);

#define PHASE(qc, par, STMT, VMSTMT) { \
  bf16x8 af[2][2]; \
  if ((qc) == 0) { LDB(par); } \
  LDA(par, qc); \
  STMT \
  __builtin_amdgcn_s_barrier(); \
  asm volatile("s_waitcnt lgkmcnt(0)" ::: "memory"); \
  __builtin_amdgcn_sched_barrier(0); \
  __builtin_amdgcn_s_setprio(1); \
  MMQ(qc); \
  __builtin_amdgcn_s_setprio(0); \
  VMSTMT \
  __builtin_amdgcn_s_barrier(); }

template<int EPI>
__global__ __launch_bounds__(512, 2) void gemm256_k(
    const bf16* __restrict__ A, const bf16* __restrict__ BT,
    float* __restrict__ C0, float* __restrict__ C1, bf16* __restrict__ Cb,
    bf16* __restrict__ qb, bf16* __restrict__ kb, bf16* __restrict__ vT,
    const float* __restrict__ cosT, const float* __restrict__ sinT,
    int N, int ldk, int nbn, int npair, int ksplit) {
  __shared__ __align__(16) char lds[131072];
  int tid = threadIdx.x;
  int l = tid & 63, lg = l >> 4, lm = l & 15;
  int w = tid >> 6, wm = w >> 2, wn = w & 3;
  int bid = blockIdx.x, kbeg = 0;
  float* C = C0;
  if (ksplit) {
    int half = gridDim.x >> 1;
    if (bid >= half) { bid -= half; kbeg = ksplit; C = C1; }
  }
  int bm = bid / nbn, bn = bid - bm * nbn;
  int m0 = bm << 8, n0 = bn << 8;
  int Bmax = N - 1;
  f32x4 acc[8][4] = {};
  bf16x8 bq[4][2];

  auto STG = [&](int slot, const bf16* mat, int rowBase, int rowMax, int kbase) {
#pragma unroll
    for (int rep = 0; rep < 2; ++rep) {
      int gi = (rep << 9) + tid;
      int row = gi >> 3, g = gi & 7;
      int gr = rowBase + row; if (gr > rowMax) gr = rowMax;
      gload16(mat + (size_t)gr * ldk + kbase + ((g ^ (row & 7)) << 3),
              lds + slot * 16384 + gi * 16);
    }
  };

  // prologue: K-tile0 fully (slots 0-3), K-tile1 B halves (slots 6,7)
  STG(0, A, m0, 2047, kbeg);
  STG(1, A, m0 + 128, 2047, kbeg);
  STG(2, BT, n0, Bmax, kbeg);
  STG(3, BT, n0 + 128, Bmax, kbeg);
  STG(6, BT, n0, Bmax, kbeg + 64);
  STG(7, BT, n0 + 128, Bmax, kbeg + 64);
  asm volatile("s_waitcnt vmcnt(4)" ::: "memory");
  __builtin_amdgcn_s_barrier();

  for (int i = 0; i < npair; ++i) {
    int kt = kbeg + (i << 7);
    bool pf = (i + 1 < npair);
    PHASE(0, 0, { STG(4, A, m0, 2047, kt + 64); }, ;)
    PHASE(1, 0, { STG(5, A, m0 + 128, 2047, kt + 64); }, ;)
    PHASE(2, 0, { if (pf) STG(2, BT, n0, Bmax, kt + 128); }, ;)
    PHASE(3, 0, { if (pf) STG(3, BT, n0 + 128, Bmax, kt + 128); },
          { if (pf) { asm volatile("s_waitcnt vmcnt(4)" ::: "memory"); }
            else    { asm volatile("s_waitcnt vmcnt(0)" ::: "memory"); } })
    PHASE(0, 1, { if (pf) STG(0, A, m0, 2047, kt + 128); }, ;)
    PHASE(1, 1, { if (pf) STG(1, A, m0 + 128, 2047, kt + 128); }, ;)
    PHASE(2, 1, { if (pf) STG(6, BT, n0, Bmax, kt + 192); }, ;)
    PHASE(3, 1, { if (pf) STG(7, BT, n0 + 128, Bmax, kt + 192); },
          { if (pf) { asm volatile("s_waitcnt vmcnt(4)" ::: "memory"); } })
  }

  if (EPI == 2) {
    // fused RoPE + layout epilogue. Wave owns head-slot h64 = bn*4 + wn.
    int h64 = (n0 >> 6) + wn;
    int tbase = m0 + (wm << 7) + lg * 4;
    if (h64 < 72) {
      bool isK = (h64 >= 64);
      bf16* outp = isK ? kb : qb;
      size_t ostr = isK ? 512 : 4096;
      int hd0 = (isK ? (h64 - 64) : h64) << 6;
      float scl = isK ? 1.0f : 0.125f;
#pragma unroll
      for (int nf = 0; nf < 2; ++nf) {
        int d31 = nf * 16 + lm;
        const float* ct = cosT + (size_t)d31 * 2048;
        const float* st = sinT + (size_t)d31 * 2048;
#pragma unroll
        for (int mf = 0; mf < 8; ++mf) {
          int t0 = tbase + mf * 16;
          float4 c4 = *(const float4*)(ct + t0);
          float4 s4 = *(const float4*)(st + t0);
          float cc[4] = {c4.x, c4.y, c4.z, c4.w};
          float ss[4] = {s4.x, s4.y, s4.z, s4.w};
#pragma unroll
          for (int j = 0; j < 4; ++j) {
            float x1 = acc[mf][nf][j], x2 = acc[mf][nf + 2][j];
            outp[(size_t)(t0 + j) * ostr + hd0 + d31] =
                __float2bfloat16((x1 * cc[j] - x2 * ss[j]) * scl);
            outp[(size_t)(t0 + j) * ostr + hd0 + d31 + 32] =
                __float2bfloat16((x2 * cc[j] + x1 * ss[j]) * scl);
          }
        }
      }
    } else {
      int kvh = h64 - 72;
#pragma unroll
      for (int nf = 0; nf < 4; ++nf) {
        int d = nf * 16 + lm;
#pragma unroll
        for (int mf = 0; mf < 8; ++mf)
#pragma unroll
          for (int j = 0; j < 4; ++j) {
            int t = tbase + mf * 16 + j;
            int b = t >> 10, s = t & 1023;
            vT[((size_t)(b * 8 + kvh) * 64 + d) * 1024 + s] = __float2bfloat16(acc[mf][nf][j]);
          }
      }
    }
    return;
  }

#pragma unroll
  for (int mf = 0; mf < 8; ++mf)
#pragma unroll
    for (int nf = 0; nf < 4; ++nf) {
      int col = n0 + (wn << 6) + nf * 16 + lm;
      if (col >= N) continue;
      int row = m0 + (wm << 7) + mf * 16 + lg * 4;
      if (EPI == 1) {
#pragma unroll
        for (int j = 0; j < 4; ++j)
          Cb[(size_t)(row + j) * N + col] = __float2bfloat16(acc[mf][nf][j]);
      } else {
#pragma unroll
        for (int j = 0; j < 4; ++j)
          C[(size_t)(row + j) * N + col] = acc[mf][nf][j];
      }
    }
}

// ---------------- flash attention, sliding window 128, sinks ----------------
__global__ __launch_bounds__(256) void attn_k(const bf16* __restrict__ Q,
                                              const bf16* __restrict__ Kg,
                                              const bf16* __restrict__ VT,
                                              const float* __restrict__ sinks,
                                              bf16* __restrict__ Og) {
  __shared__ __align__(16) bf16 Qs[128 * 64];
  __shared__ __align__(16) bf16 Ks[128 * 64];
  __shared__ __align__(16) bf16 Vs[64 * 128];
  __shared__ __align__(16) bf16 Ps[4][32 * 128];
  int bid = blockIdx.x;
  int b = bid >> 9, rest = bid & 511, h = rest >> 3, qt = rest & 7;
  int q0 = qt * 128, kvh = h >> 3;
  int tid = threadIdx.x, w = tid >> 6, l = tid & 63, lg = l >> 4, lm = l & 15;

  float mrun[2][4], lrun[2][4];
  float ls = __logf(sinks[h]);
#pragma unroll
  for (int mi = 0; mi < 2; ++mi)
#pragma unroll
    for (int j = 0; j < 4; ++j) { mrun[mi][j] = ls; lrun[mi][j] = 1.0f; }
  f32x4 oacc[2][4] = {};

#pragma unroll
  for (int g = 0; g < 4; ++g) {
    int c = g * 256 + w * 64 + l;
    int r = c >> 3, kc = (c & 7) * 8;
    gload16(Q + ((size_t)(b * 1024 + q0 + r)) * QSZ + h * 64 + kc,
            (char*)Qs + (size_t)(g * 256 + w * 64) * 16);
  }

  for (int t = (q0 == 0) ? 1 : 0; t < 2; ++t) {
    int kb = q0 - 128 + t * 128;
#pragma unroll
    for (int g = 0; g < 4; ++g) {
      int c = g * 256 + w * 64 + l;
      int r = c >> 3, kc = (c & 7) * 8;
      gload16(Kg + ((size_t)(b * 1024 + kb + r)) * 512 + kvh * 64 + kc,
              (char*)Ks + (size_t)(g * 256 + w * 64) * 16);
      int rv = c >> 4, kv = (c & 15) * 8;
      gload16(VT + ((size_t)(b * 8 + kvh) * 64 + rv) * 1024 + kb + kv,
              (char*)Vs + (size_t)(g * 256 + w * 64) * 16);
    }
    __syncthreads();

    f32x4 sacc[2][8] = {};
#pragma unroll
    for (int kk = 0; kk < 2; ++kk) {
      bf16x8 qf[2], kf[8];
#pragma unroll
      for (int mi = 0; mi < 2; ++mi)
        qf[mi] = *reinterpret_cast<const bf16x8*>(&Qs[(w * 32 + mi * 16 + lm) * 64 + kk * 32 + lg * 8]);
#pragma unroll
      for (int ni = 0; ni < 8; ++ni)
        kf[ni] = *reinterpret_cast<const bf16x8*>(&Ks[(ni * 16 + lm) * 64 + kk * 32 + lg * 8]);
#pragma unroll
      for (int mi = 0; mi < 2; ++mi)
#pragma unroll
        for (int ni = 0; ni < 8; ++ni)
          sacc[mi][ni] = __builtin_amdgcn_mfma_f32_16x16x32_bf16(qf[mi], kf[ni], sacc[mi][ni], 0, 0, 0);
    }

#pragma unroll
    for (int mi = 0; mi < 2; ++mi)
#pragma unroll
      for (int j = 0; j < 4; ++j) {
        int qi = q0 + w * 32 + mi * 16 + lg * 4 + j;
        float mx = -1e30f;
#pragma unroll
        for (int ni = 0; ni < 8; ++ni) {
          int kg = kb + ni * 16 + lm;
          float v = sacc[mi][ni][j];
          v = (kg <= qi && kg >= qi - 127) ? v : -1e30f;
          sacc[mi][ni][j] = v;
          mx = fmaxf(mx, v);
        }
#pragma unroll
        for (int d = 1; d < 16; d <<= 1) mx = fmaxf(mx, __shfl_xor(mx, d, 64));
        float mnew = fmaxf(mrun[mi][j], mx);
        float sum = 0.f;
#pragma unroll
        for (int ni = 0; ni < 8; ++ni) {
          float p = __expf(sacc[mi][ni][j] - mnew);
          sacc[mi][ni][j] = p;
          sum += p;
        }
#pragma unroll
        for (int d = 1; d < 16; d <<= 1) sum += __shfl_xor(sum, d, 64);
        float alpha = __expf(mrun[mi][j] - mnew);
        lrun[mi][j] = lrun[mi][j] * alpha + sum;
        mrun[mi][j] = mnew;
#pragma unroll
        for (int ni = 0; ni < 4; ++ni) oacc[mi][ni][j] *= alpha;
#pragma unroll
        for (int ni = 0; ni < 8; ++ni)
          Ps[w][(mi * 16 + lg * 4 + j) * 128 + ni * 16 + lm] = __float2bfloat16(sacc[mi][ni][j]);
      }

#pragma unroll
    for (int ks = 0; ks < 4; ++ks) {
      bf16x8 pf[2], vf[4];
#pragma unroll
      for (int mi = 0; mi < 2; ++mi)
        pf[mi] = *reinterpret_cast<const bf16x8*>(&Ps[w][(mi * 16 + lm) * 128 + ks * 32 + lg * 8]);
#pragma unroll
      for (int ni = 0; ni < 4; ++ni)
        vf[ni] = *reinterpret_cast<const bf16x8*>(&Vs[(ni * 16 + lm) * 128 + ks * 32 + lg * 8]);
#pragma unroll
      for (int mi = 0; mi < 2; ++mi)
#pragma unroll
        for (int ni = 0; ni < 4; ++ni)
          oacc[mi][ni] = __builtin_amdgcn_mfma_f32_16x16x32_bf16(pf[mi], vf[ni], oacc[mi][ni], 0, 0, 0);
    }
    __syncthreads();
  }

#pragma unroll
  for (int mi = 0; mi < 2; ++mi)
#pragma unroll
    for (int ni = 0; ni < 4; ++ni)
#pragma unroll
      for (int j = 0; j < 4; ++j) {
        int tok = b * 1024 + q0 + w * 32 + mi * 16 + lg * 4 + j;
        Og[(size_t)tok * QSZ + h * 64 + ni * 16 + lm] =
            __float2bfloat16(oacc[mi][ni][j] / lrun[mi][j]);
      }
}

// ---------------- add two f32 partials -> f32 out ----------------
__global__ __launch_bounds__(256) void add2_k(const float* __restrict__ a,
                                              const float* __restrict__ b,
                                              float* __restrict__ o, int n4) {
  int i = blockIdx.x * 256 + threadIdx.x;
  if (i >= n4) return;
  float4 x = reinterpret_cast<const float4*>(a)[i];
  float4 y = reinterpret_cast<const float4*>(b)[i];
  reinterpret_cast<float4*>(o)[i] = make_float4(x.x + y.x, x.y + y.y, x.z + y.z, x.w + y.w);
}

extern "C" void kernel_launch(void* const* d_in, const int* in_sizes, int n_in,
                              void* d_out, int out_size, void* d_ws, size_t ws_size,
                              hipStream_t stream) {
  const int*   positions = (const int*)d_in[0];
  const float* hidden    = (const float*)d_in[1];
  const float* w_qkv     = (const float*)d_in[2];
  const float* w_o       = (const float*)d_in[3];
  const float* sinks     = (const float*)d_in[4];
  float* out = (float*)d_out;

  char* ws = (char*)d_ws;
  bf16*  wqkvT = (bf16*)(ws + 0);            // [5120][2944]  = 30,146,560 B
  bf16*  woT   = (bf16*)(ws + 30146560);     // [2880][4096]  = 23,592,960
  bf16*  qb    = (bf16*)(ws + 53739520);     // [2048][4096]  = 16,777,216
  bf16*  kb    = (bf16*)(ws + 70516736);     // [2048][512]   =  2,097,152
  bf16*  vT    = (bf16*)(ws + 72613888);     // [16*64][1024] =  2,097,152
  bf16*  attnb = (bf16*)(ws + 74711040);     // [2048][4096]  = 16,777,216
  bf16*  hid_b = (bf16*)(ws + 91488256);     // [2048][2944]  = 12,058,624 (dead after QKV)
  float* cosT  = (float*)(ws + 103546880);   // [32][2048] f32 = 262,144   (dead after QKV)
  float* sinT  = (float*)(ws + 103809024);   // 262,144                    (dead after QKV)
  float* Cp0   = (float*)(ws + 91488256);    // overlay hid_b/cosT/sinT: [2048][2880] f32
  float* Cp1   = (float*)(ws + 115081216);   // ends 138,674,176

  // 1. tables + conversions (K zero-padded to 2944)
  sincos_k<<<(32 * 2048) / 256, 256, 0, stream>>>(positions, cosT, sinT);
  cvt_pad_k<<<2944, 256, 0, stream>>>(hidden, hid_b, NTOK, HIDDEN, KPAD);
  transpose_cvt_k<<<dim3(QKVN / 64, KPAD / 64), 256, 0, stream>>>(w_qkv, wqkvT, HIDDEN, QKVN, KPAD);
  transpose_cvt_k<<<dim3(HIDDEN / 64, QSZ / 64), 256, 0, stream>>>(w_o, woT, QSZ, HIDDEN, QSZ);
  // 2. QKV projection + fused RoPE/layout epilogue
  gemm256_k<2><<<(NTOK / 256) * (QKVN / 256), 512, 0, stream>>>(
      hid_b, wqkvT, nullptr, nullptr, nullptr, qb, kb, vT, cosT, sinT,
      QKVN, KPAD, QKVN / 256, KPAD / 128, 0);
  // 3. attention
  attn_k<<<2 * NH * (SEQ / 128), 256, 0, stream>>>(qb, kb, vT, sinks, attnb);
  // 4. output projection with 2-way K-split -> 2 f32 partials
  gemm256_k<0><<<2 * (NTOK / 256) * 12, 512, 0, stream>>>(
      attnb, woT, Cp0, Cp1, nullptr, nullptr, nullptr, nullptr, nullptr, nullptr,
      HIDDEN, QSZ, 12, 16, 2048);
  // 5. partial sum -> out
  add2_k<<<(NTOK * HIDDEN / 4) / 256, 256, 0, stream>>>(Cp0, Cp1, out, NTOK * HIDDEN / 4);
}

// Round 5
// 222.112 us; speedup vs baseline: 1.4646x; 1.0983x over previous
//
#include <hip/hip_runtime.h>
#include <hip/hip_bf16.h>
#include <stdint.h>

typedef __hip_bfloat16 bf16;
typedef short bf16x8 __attribute__((ext_vector_type(8)));
typedef float f32x4 __attribute__((ext_vector_type(4)));

#define NTOK 2048
#define HIDDEN 2880
#define KPAD 2944
#define QKVN 5120
#define QSZ 4096
#define NH 64
#define NKV 8
#define HD 64
#define SEQ 1024

__device__ __forceinline__ void gload16(const void* g, void* l) {
  __builtin_amdgcn_global_load_lds(
      (const __attribute__((address_space(1))) uint32_t*)g,
      (__attribute__((address_space(3))) uint32_t*)l, 16, 0, 0);
}

// =====================================================================================
// prep_k: one launch doing (a) w_qkv transpose->bf16 [5120][2944], (b) hidden->bf16
// padded [2048][2944], (c) sincos tables. All independent.
// blocks: [0,3680) transpose tiles, [3680,6624) cvt, [6624,6880) sincos. 256 thr.
// =====================================================================================
__global__ __launch_bounds__(256) void prep_k(const float* __restrict__ w_qkv,
                                              bf16* __restrict__ wqkvT,
                                              const float* __restrict__ hidden,
                                              bf16* __restrict__ hid_b,
                                              const int* __restrict__ positions,
                                              float* __restrict__ cosT,
                                              float* __restrict__ sinT) {
  __shared__ float t[64][68];
  int bid = blockIdx.x, tid = threadIdx.x;
  if (bid < 3680) {
    // transpose w_qkv[2880][5120] -> wqkvT[5120][2944] (zero pad rows >= 2880)
    int tx = bid % 80, ty = bid / 80;
    int c0 = tx * 64, r0 = ty * 64;
    int lr = tid >> 2, lc4 = (tid & 3) << 4;
    int r = r0 + lr;
    if (r < HIDDEN) {
      const float* s = w_qkv + (size_t)r * QKVN + c0 + lc4;
      *(float4*)&t[lr][lc4 + 0]  = *(const float4*)(s + 0);
      *(float4*)&t[lr][lc4 + 4]  = *(const float4*)(s + 4);
      *(float4*)&t[lr][lc4 + 8]  = *(const float4*)(s + 8);
      *(float4*)&t[lr][lc4 + 12] = *(const float4*)(s + 12);
    } else {
      float4 z = make_float4(0.f, 0.f, 0.f, 0.f);
      *(float4*)&t[lr][lc4 + 0]  = z; *(float4*)&t[lr][lc4 + 4]  = z;
      *(float4*)&t[lr][lc4 + 8]  = z; *(float4*)&t[lr][lc4 + 12] = z;
    }
    __syncthreads();
    int dr = tid >> 2;
#pragma unroll
    for (int rep = 0; rep < 2; ++rep) {
      int dc0 = (tid & 3) * 16 + rep * 8;
      bf16 o[8];
#pragma unroll
      for (int k = 0; k < 8; ++k) o[k] = __float2bfloat16(t[dc0 + k][dr]);
      *(uint4*)(wqkvT + (size_t)(c0 + dr) * KPAD + r0 + dc0) = *(const uint4*)o;
    }
  } else if (bid < 6624) {
    int gpr = KPAD >> 3;
    int i = (bid - 3680) * 256 + tid;
    if (i >= NTOK * gpr) return;
    int r = i / gpr, c8 = (i - r * gpr) << 3;
    bf16 o[8];
    if (c8 < HIDDEN) {
      const float4 v0 = *(const float4*)(hidden + (size_t)r * HIDDEN + c8);
      const float4 v1 = *(const float4*)(hidden + (size_t)r * HIDDEN + c8 + 4);
      o[0] = __float2bfloat16(v0.x); o[1] = __float2bfloat16(v0.y);
      o[2] = __float2bfloat16(v0.z); o[3] = __float2bfloat16(v0.w);
      o[4] = __float2bfloat16(v1.x); o[5] = __float2bfloat16(v1.y);
      o[6] = __float2bfloat16(v1.z); o[7] = __float2bfloat16(v1.w);
    } else {
#pragma unroll
      for (int j = 0; j < 8; ++j) o[j] = __float2bfloat16(0.f);
    }
    *(uint4*)(hid_b + (size_t)r * KPAD + c8) = *(const uint4*)o;
  } else {
    int i = (bid - 6624) * 256 + tid;   // 32*2048 total
    int d = i >> 11, tt = i & 2047;
    float inv = powf(150000.0f, -(float)d / 32.0f);
    float a = (float)positions[tt] * inv;
    cosT[i] = cosf(a);
    sinT[i] = sinf(a);
  }
}

// =====================================================================================
// 256x256 8-phase bf16 GEMM (T2 swizzle + T3/T4 counted vmcnt + T5 setprio)
// EPI=0: C f32 (C0/C1 by ksplit half). EPI=2: fused RoPE epilogue + woT-transpose
// tail blocks (bid>=160 transpose w_o -> woT while idle CUs wait).
// =====================================================================================
#define LDB(par) { \
  const char* _bb = lds + (((par)*4 + 2 + (wn>>1)) << 14); \
  _Pragma("unroll") \
  for (int _n = 0; _n < 4; ++_n) { \
    int _r = ((wn&1)<<6) + _n*16 + lm; \
    _Pragma("unroll") \
    for (int _kk = 0; _kk < 2; ++_kk) \
      bq[_n][_kk] = *(const bf16x8*)(_bb + _r*128 + (((_kk*4 + lg) ^ (_r & 7)) << 4)); } }

#define LDA(par, qc) { \
  const char* _ab = lds + (((par)*4 + wm) << 14); \
  _Pragma("unroll") \
  for (int _f = 0; _f < 2; ++_f) { \
    int _r = (qc)*32 + _f*16 + lm; \
    _Pragma("unroll") \
    for (int _kk = 0; _kk < 2; ++_kk) \
      af[_f][_kk] = *(const bf16x8*)(_ab + _r*128 + (((_kk*4 + lg) ^ (_r & 7)) << 4)); } }

#define MMQ(qc) \
  _Pragma("unroll") \
  for (int _kk = 0; _kk < 2; ++_kk) \
  _Pragma("unroll") \
  for (int _f = 0; _f < 2; ++_f) \
  _Pragma("unroll") \
  for (int _n = 0; _n < 4; ++_n) \
    acc[(qc)*2 + _f][_n] = __builtin_amdgcn_mfma_f32_16x16x32_bf16( \
        af[_f][_kk], bq[_n][_kk], acc[(qc)*2 + _f][_n], 0, 0, 0);

#define PHASE(qc, par, STMT, VMSTMT) { \
  bf16x8 af[2][2]; \
  if ((qc) == 0) { LDB(par); } \
  LDA(par, qc); \
  STMT \
  __builtin_amdgcn_s_barrier(); \
  asm volatile("s_waitcnt lgkmcnt(0)" ::: "memory"); \
  __builtin_amdgcn_sched_barrier(0); \
  __builtin_amdgcn_s_setprio(1); \
  MMQ(qc); \
  __builtin_amdgcn_s_setprio(0); \
  VMSTMT \
  __builtin_amdgcn_s_barrier(); }

template<int EPI>
__global__ __launch_bounds__(512, 2) void gemm256_k(
    const bf16* __restrict__ A, const bf16* __restrict__ BT,
    float* __restrict__ C0, float* __restrict__ C1,
    bf16* __restrict__ qb, bf16* __restrict__ kb, bf16* __restrict__ vT,
    const float* __restrict__ cosT, const float* __restrict__ sinT,
    const float* __restrict__ wo, bf16* __restrict__ woT,
    int N, int ldk, int nbn, int npair, int ksplit) {
  __shared__ __align__(16) char lds[131072];
  int tid = threadIdx.x;
  int bid = blockIdx.x;

  if (EPI == 2 && bid >= 160) {
    // ---- tail blocks: transpose w_o[4096][2880] -> woT[2880][4096], 2 tiles/block ----
    int i = bid - 160;                 // 0..1439
    int half = tid >> 8;               // two 64x64 tiles per block
    int t = i * 2 + half;              // 0..2879
    int tx = t % 45, ty = t / 45;
    int c0 = tx * 64, r0 = ty * 64;
    int tid2 = tid & 255;
    float* tb = (float*)lds + half * (64 * 68);
    int lr = tid2 >> 2, lc4 = (tid2 & 3) << 4;
    const float* s = wo + (size_t)(r0 + lr) * HIDDEN + c0 + lc4;
    *(float4*)&tb[lr * 68 + lc4 + 0]  = *(const float4*)(s + 0);
    *(float4*)&tb[lr * 68 + lc4 + 4]  = *(const float4*)(s + 4);
    *(float4*)&tb[lr * 68 + lc4 + 8]  = *(const float4*)(s + 8);
    *(float4*)&tb[lr * 68 + lc4 + 12] = *(const float4*)(s + 12);
    __syncthreads();
    int dr = tid2 >> 2;
#pragma unroll
    for (int rep = 0; rep < 2; ++rep) {
      int dc0 = (tid2 & 3) * 16 + rep * 8;
      bf16 o[8];
#pragma unroll
      for (int k = 0; k < 8; ++k) o[k] = __float2bfloat16(tb[(dc0 + k) * 68 + dr]);
      *(uint4*)(woT + (size_t)(c0 + dr) * QSZ + r0 + dc0) = *(const uint4*)o;
    }
    return;
  }

  int l = tid & 63, lg = l >> 4, lm = l & 15;
  int w = tid >> 6, wm = w >> 2, wn = w & 3;
  int kbeg = 0;
  float* C = C0;
  if (ksplit) {
    int half = gridDim.x >> 1;
    if (bid >= half) { bid -= half; kbeg = ksplit; C = C1; }
  }
  int bm = bid / nbn, bn = bid - bm * nbn;
  int m0 = bm << 8, n0 = bn << 8;
  int Bmax = N - 1;
  f32x4 acc[8][4] = {};
  bf16x8 bq[4][2];

  auto STG = [&](int slot, const bf16* mat, int rowBase, int rowMax, int kbase) {
#pragma unroll
    for (int rep = 0; rep < 2; ++rep) {
      int gi = (rep << 9) + tid;
      int row = gi >> 3, g = gi & 7;
      int gr = rowBase + row; if (gr > rowMax) gr = rowMax;
      gload16(mat + (size_t)gr * ldk + kbase + ((g ^ (row & 7)) << 3),
              lds + slot * 16384 + gi * 16);
    }
  };

  // prologue: K-tile0 fully (slots 0-3), K-tile1 B halves (slots 6,7)
  STG(0, A, m0, 2047, kbeg);
  STG(1, A, m0 + 128, 2047, kbeg);
  STG(2, BT, n0, Bmax, kbeg);
  STG(3, BT, n0 + 128, Bmax, kbeg);
  STG(6, BT, n0, Bmax, kbeg + 64);
  STG(7, BT, n0 + 128, Bmax, kbeg + 64);
  asm volatile("s_waitcnt vmcnt(4)" ::: "memory");
  __builtin_amdgcn_s_barrier();

  for (int i = 0; i < npair; ++i) {
    int kt = kbeg + (i << 7);
    bool pf = (i + 1 < npair);
    PHASE(0, 0, { STG(4, A, m0, 2047, kt + 64); }, ;)
    PHASE(1, 0, { STG(5, A, m0 + 128, 2047, kt + 64); }, ;)
    PHASE(2, 0, { if (pf) STG(2, BT, n0, Bmax, kt + 128); }, ;)
    PHASE(3, 0, { if (pf) STG(3, BT, n0 + 128, Bmax, kt + 128); },
          { if (pf) { asm volatile("s_waitcnt vmcnt(4)" ::: "memory"); }
            else    { asm volatile("s_waitcnt vmcnt(0)" ::: "memory"); } })
    PHASE(0, 1, { if (pf) STG(0, A, m0, 2047, kt + 128); }, ;)
    PHASE(1, 1, { if (pf) STG(1, A, m0 + 128, 2047, kt + 128); }, ;)
    PHASE(2, 1, { if (pf) STG(6, BT, n0, Bmax, kt + 192); }, ;)
    PHASE(3, 1, { if (pf) STG(7, BT, n0 + 128, Bmax, kt + 192); },
          { if (pf) { asm volatile("s_waitcnt vmcnt(4)" ::: "memory"); } })
  }

  if (EPI == 2) {
    // fused RoPE + layout epilogue. Wave owns head-slot h64 = bn*4 + wn.
    int h64 = (n0 >> 6) + wn;
    int tbase = m0 + (wm << 7) + lg * 4;
    if (h64 < 72) {
      bool isK = (h64 >= 64);
      bf16* outp = isK ? kb : qb;
      size_t ostr = isK ? 512 : 4096;
      int hd0 = (isK ? (h64 - 64) : h64) << 6;
      float scl = isK ? 1.0f : 0.125f;
#pragma unroll
      for (int nf = 0; nf < 2; ++nf) {
        int d31 = nf * 16 + lm;
        const float* ct = cosT + (size_t)d31 * 2048;
        const float* st = sinT + (size_t)d31 * 2048;
#pragma unroll
        for (int mf = 0; mf < 8; ++mf) {
          int t0 = tbase + mf * 16;
          float4 c4 = *(const float4*)(ct + t0);
          float4 s4 = *(const float4*)(st + t0);
          float cc[4] = {c4.x, c4.y, c4.z, c4.w};
          float ss[4] = {s4.x, s4.y, s4.z, s4.w};
#pragma unroll
          for (int j = 0; j < 4; ++j) {
            float x1 = acc[mf][nf][j], x2 = acc[mf][nf + 2][j];
            outp[(size_t)(t0 + j) * ostr + hd0 + d31] =
                __float2bfloat16((x1 * cc[j] - x2 * ss[j]) * scl);
            outp[(size_t)(t0 + j) * ostr + hd0 + d31 + 32] =
                __float2bfloat16((x2 * cc[j] + x1 * ss[j]) * scl);
          }
        }
      }
    } else {
      int kvh = h64 - 72;
#pragma unroll
      for (int nf = 0; nf < 4; ++nf) {
        int d = nf * 16 + lm;
#pragma unroll
        for (int mf = 0; mf < 8; ++mf)
#pragma unroll
          for (int j = 0; j < 4; ++j) {
            int t = tbase + mf * 16 + j;
            int b = t >> 10, s = t & 1023;
            vT[((size_t)(b * 8 + kvh) * 64 + d) * 1024 + s] = __float2bfloat16(acc[mf][nf][j]);
          }
      }
    }
    return;
  }

#pragma unroll
  for (int mf = 0; mf < 8; ++mf)
#pragma unroll
    for (int nf = 0; nf < 4; ++nf) {
      int col = n0 + (wn << 6) + nf * 16 + lm;
      if (col >= N) continue;
      int row = m0 + (wm << 7) + mf * 16 + lg * 4;
#pragma unroll
      for (int j = 0; j < 4; ++j)
        C[(size_t)(row + j) * N + col] = acc[mf][nf][j];
    }
}

// ---------------- flash attention, sliding window 128, sinks ----------------
__global__ __launch_bounds__(256) void attn_k(const bf16* __restrict__ Q,
                                              const bf16* __restrict__ Kg,
                                              const bf16* __restrict__ VT,
                                              const float* __restrict__ sinks,
                                              bf16* __restrict__ Og) {
  __shared__ __align__(16) bf16 Qs[128 * 64];
  __shared__ __align__(16) bf16 Ks[128 * 64];
  __shared__ __align__(16) bf16 Vs[64 * 128];
  __shared__ __align__(16) bf16 Ps[4][32 * 128];
  int bid = blockIdx.x;
  int b = bid >> 9, rest = bid & 511, h = rest >> 3, qt = rest & 7;
  int q0 = qt * 128, kvh = h >> 3;
  int tid = threadIdx.x, w = tid >> 6, l = tid & 63, lg = l >> 4, lm = l & 15;

  float mrun[2][4], lrun[2][4];
  float ls = __logf(sinks[h]);
#pragma unroll
  for (int mi = 0; mi < 2; ++mi)
#pragma unroll
    for (int j = 0; j < 4; ++j) { mrun[mi][j] = ls; lrun[mi][j] = 1.0f; }
  f32x4 oacc[2][4] = {};

#pragma unroll
  for (int g = 0; g < 4; ++g) {
    int c = g * 256 + w * 64 + l;
    int r = c >> 3, kc = (c & 7) * 8;
    gload16(Q + ((size_t)(b * 1024 + q0 + r)) * QSZ + h * 64 + kc,
            (char*)Qs + (size_t)(g * 256 + w * 64) * 16);
  }

  for (int t = (q0 == 0) ? 1 : 0; t < 2; ++t) {
    int kb = q0 - 128 + t * 128;
#pragma unroll
    for (int g = 0; g < 4; ++g) {
      int c = g * 256 + w * 64 + l;
      int r = c >> 3, kc = (c & 7) * 8;
      gload16(Kg + ((size_t)(b * 1024 + kb + r)) * 512 + kvh * 64 + kc,
              (char*)Ks + (size_t)(g * 256 + w * 64) * 16);
      int rv = c >> 4, kv = (c & 15) * 8;
      gload16(VT + ((size_t)(b * 8 + kvh) * 64 + rv) * 1024 + kb + kv,
              (char*)Vs + (size_t)(g * 256 + w * 64) * 16);
    }
    __syncthreads();

    f32x4 sacc[2][8] = {};
#pragma unroll
    for (int kk = 0; kk < 2; ++kk) {
      bf16x8 qf[2], kf[8];
#pragma unroll
      for (int mi = 0; mi < 2; ++mi)
        qf[mi] = *reinterpret_cast<const bf16x8*>(&Qs[(w * 32 + mi * 16 + lm) * 64 + kk * 32 + lg * 8]);
#pragma unroll
      for (int ni = 0; ni < 8; ++ni)
        kf[ni] = *reinterpret_cast<const bf16x8*>(&Ks[(ni * 16 + lm) * 64 + kk * 32 + lg * 8]);
#pragma unroll
      for (int mi = 0; mi < 2; ++mi)
#pragma unroll
        for (int ni = 0; ni < 8; ++ni)
          sacc[mi][ni] = __builtin_amdgcn_mfma_f32_16x16x32_bf16(qf[mi], kf[ni], sacc[mi][ni], 0, 0, 0);
    }

#pragma unroll
    for (int mi = 0; mi < 2; ++mi)
#pragma unroll
      for (int j = 0; j < 4; ++j) {
        int qi = q0 + w * 32 + mi * 16 + lg * 4 + j;
        float mx = -1e30f;
#pragma unroll
        for (int ni = 0; ni < 8; ++ni) {
          int kg = kb + ni * 16 + lm;
          float v = sacc[mi][ni][j];
          v = (kg <= qi && kg >= qi - 127) ? v : -1e30f;
          sacc[mi][ni][j] = v;
          mx = fmaxf(mx, v);
        }
#pragma unroll
        for (int d = 1; d < 16; d <<= 1) mx = fmaxf(mx, __shfl_xor(mx, d, 64));
        float mnew = fmaxf(mrun[mi][j], mx);
        float sum = 0.f;
#pragma unroll
        for (int ni = 0; ni < 8; ++ni) {
          float p = __expf(sacc[mi][ni][j] - mnew);
          sacc[mi][ni][j] = p;
          sum += p;
        }
#pragma unroll
        for (int d = 1; d < 16; d <<= 1) sum += __shfl_xor(sum, d, 64);
        float alpha = __expf(mrun[mi][j] - mnew);
        lrun[mi][j] = lrun[mi][j] * alpha + sum;
        mrun[mi][j] = mnew;
#pragma unroll
        for (int ni = 0; ni < 4; ++ni) oacc[mi][ni][j] *= alpha;
#pragma unroll
        for (int ni = 0; ni < 8; ++ni)
          Ps[w][(mi * 16 + lg * 4 + j) * 128 + ni * 16 + lm] = __float2bfloat16(sacc[mi][ni][j]);
      }

#pragma unroll
    for (int ks = 0; ks < 4; ++ks) {
      bf16x8 pf[2], vf[4];
#pragma unroll
      for (int mi = 0; mi < 2; ++mi)
        pf[mi] = *reinterpret_cast<const bf16x8*>(&Ps[w][(mi * 16 + lm) * 128 + ks * 32 + lg * 8]);
#pragma unroll
      for (int ni = 0; ni < 4; ++ni)
        vf[ni] = *reinterpret_cast<const bf16x8*>(&Vs[(ni * 16 + lm) * 128 + ks * 32 + lg * 8]);
#pragma unroll
      for (int mi = 0; mi < 2; ++mi)
#pragma unroll
        for (int ni = 0; ni < 4; ++ni)
          oacc[mi][ni] = __builtin_amdgcn_mfma_f32_16x16x32_bf16(pf[mi], vf[ni], oacc[mi][ni], 0, 0, 0);
    }
    __syncthreads();
  }

#pragma unroll
  for (int mi = 0; mi < 2; ++mi)
#pragma unroll
    for (int ni = 0; ni < 4; ++ni)
#pragma unroll
      for (int j = 0; j < 4; ++j) {
        int tok = b * 1024 + q0 + w * 32 + mi * 16 + lg * 4 + j;
        Og[(size_t)tok * QSZ + h * 64 + ni * 16 + lm] =
            __float2bfloat16(oacc[mi][ni][j] / lrun[mi][j]);
      }
}

// ---------------- add two f32 partials -> f32 out ----------------
__global__ __launch_bounds__(256) void add2_k(const float* __restrict__ a,
                                              const float* __restrict__ b,
                                              float* __restrict__ o, int n4) {
  int i = blockIdx.x * 256 + threadIdx.x;
  if (i >= n4) return;
  float4 x = reinterpret_cast<const float4*>(a)[i];
  float4 y = reinterpret_cast<const float4*>(b)[i];
  reinterpret_cast<float4*>(o)[i] = make_float4(x.x + y.x, x.y + y.y, x.z + y.z, x.w + y.w);
}

extern "C" void kernel_launch(void* const* d_in, const int* in_sizes, int n_in,
                              void* d_out, int out_size, void* d_ws, size_t ws_size,
                              hipStream_t stream) {
  const int*   positions = (const int*)d_in[0];
  const float* hidden    = (const float*)d_in[1];
  const float* w_qkv     = (const float*)d_in[2];
  const float* w_o       = (const float*)d_in[3];
  const float* sinks     = (const float*)d_in[4];
  float* out = (float*)d_out;

  char* ws = (char*)d_ws;
  bf16*  wqkvT = (bf16*)(ws + 0);            // [5120][2944]  = 30,146,560 B
  bf16*  woT   = (bf16*)(ws + 30146560);     // [2880][4096]  = 23,592,960
  bf16*  qb    = (bf16*)(ws + 53739520);     // [2048][4096]  = 16,777,216
  bf16*  kb    = (bf16*)(ws + 70516736);     // [2048][512]   =  2,097,152
  bf16*  vT    = (bf16*)(ws + 72613888);     // [16*64][1024] =  2,097,152
  bf16*  attnb = (bf16*)(ws + 74711040);     // [2048][4096]  = 16,777,216
  bf16*  hid_b = (bf16*)(ws + 91488256);     // [2048][2944]  = 12,058,624 (dead after QKV)
  float* cosT  = (float*)(ws + 103546880);   // [32][2048] f32 = 262,144   (dead after QKV)
  float* sinT  = (float*)(ws + 103809024);   // 262,144                    (dead after QKV)
  float* Cp0   = (float*)(ws + 91488256);    // overlay hid_b/cosT/sinT: [2048][2880] f32
  float* Cp1   = (float*)(ws + 115081216);   // ends 138,674,176

  // 1. fused prep: w_qkv transpose + hidden cvt/pad + sincos tables (one launch)
  prep_k<<<6880, 256, 0, stream>>>(w_qkv, wqkvT, hidden, hid_b, positions, cosT, sinT);
  // 2. QKV projection + fused RoPE/layout epilogue; tail blocks transpose w_o -> woT
  gemm256_k<2><<<160 + 1440, 512, 0, stream>>>(
      hid_b, wqkvT, nullptr, nullptr, qb, kb, vT, cosT, sinT, w_o, woT,
      QKVN, KPAD, QKVN / 256, KPAD / 128, 0);
  // 3. attention
  attn_k<<<2 * NH * (SEQ / 128), 256, 0, stream>>>(qb, kb, vT, sinks, attnb);
  // 4. output projection with 2-way K-split -> 2 f32 partials
  gemm256_k<0><<<2 * (NTOK / 256) * 12, 512, 0, stream>>>(
      attnb, woT, Cp0, Cp1, nullptr, nullptr, nullptr, nullptr, nullptr, nullptr, nullptr,
      HIDDEN, QSZ, 12, 16, 2048);
  // 5. partial sum -> out
  add2_k<<<(NTOK * HIDDEN / 4) / 256, 256, 0, stream>>>(Cp0, Cp1, out, NTOK * HIDDEN / 4);
}

// Round 6
// 221.011 us; speedup vs baseline: 1.4719x; 1.0050x over previous
//
#include <hip/hip_runtime.h>
#include <hip/hip_bf16.h>
#include <stdint.h>

typedef __hip_bfloat16 bf16;
typedef short bf16x8 __attribute__((ext_vector_type(8)));
typedef float f32x4 __attribute__((ext_vector_type(4)));

#define NTOK 2048
#define HIDDEN 2880
#define KPAD 2944
#define QKVN 5120
#define QSZ 4096
#define QST 4160   // padded row stride for qb/attnb/woT (breaks pow2 set-aliasing)
#define NH 64
#define NKV 8
#define HD 64
#define SEQ 1024

__device__ __forceinline__ void gload16(const void* g, void* l) {
  __builtin_amdgcn_global_load_lds(
      (const __attribute__((address_space(1))) uint32_t*)g,
      (__attribute__((address_space(3))) uint32_t*)l, 16, 0, 0);
}

// =====================================================================================
// prep_k: (a) w_qkv transpose->bf16 [5120][2944], (b) hidden->bf16 padded [2048][2944],
// (c) sincos tables. blocks: [0,3680) transpose, [3680,6624) cvt, [6624,6880) sincos.
// =====================================================================================
__global__ __launch_bounds__(256) void prep_k(const float* __restrict__ w_qkv,
                                              bf16* __restrict__ wqkvT,
                                              const float* __restrict__ hidden,
                                              bf16* __restrict__ hid_b,
                                              const int* __restrict__ positions,
                                              float* __restrict__ cosT,
                                              float* __restrict__ sinT) {
  __shared__ float t[64][68];
  int bid = blockIdx.x, tid = threadIdx.x;
  if (bid < 3680) {
    int tx = bid % 80, ty = bid / 80;
    int c0 = tx * 64, r0 = ty * 64;
    int lr = tid >> 2, lc4 = (tid & 3) << 4;
    int r = r0 + lr;
    if (r < HIDDEN) {
      const float* s = w_qkv + (size_t)r * QKVN + c0 + lc4;
      *(float4*)&t[lr][lc4 + 0]  = *(const float4*)(s + 0);
      *(float4*)&t[lr][lc4 + 4]  = *(const float4*)(s + 4);
      *(float4*)&t[lr][lc4 + 8]  = *(const float4*)(s + 8);
      *(float4*)&t[lr][lc4 + 12] = *(const float4*)(s + 12);
    } else {
      float4 z = make_float4(0.f, 0.f, 0.f, 0.f);
      *(float4*)&t[lr][lc4 + 0]  = z; *(float4*)&t[lr][lc4 + 4]  = z;
      *(float4*)&t[lr][lc4 + 8]  = z; *(float4*)&t[lr][lc4 + 12] = z;
    }
    __syncthreads();
    int dr = tid >> 2;
#pragma unroll
    for (int rep = 0; rep < 2; ++rep) {
      int dc0 = (tid & 3) * 16 + rep * 8;
      bf16 o[8];
#pragma unroll
      for (int k = 0; k < 8; ++k) o[k] = __float2bfloat16(t[dc0 + k][dr]);
      *(uint4*)(wqkvT + (size_t)(c0 + dr) * KPAD + r0 + dc0) = *(const uint4*)o;
    }
  } else if (bid < 6624) {
    int gpr = KPAD >> 3;
    int i = (bid - 3680) * 256 + tid;
    if (i >= NTOK * gpr) return;
    int r = i / gpr, c8 = (i - r * gpr) << 3;
    bf16 o[8];
    if (c8 < HIDDEN) {
      const float4 v0 = *(const float4*)(hidden + (size_t)r * HIDDEN + c8);
      const float4 v1 = *(const float4*)(hidden + (size_t)r * HIDDEN + c8 + 4);
      o[0] = __float2bfloat16(v0.x); o[1] = __float2bfloat16(v0.y);
      o[2] = __float2bfloat16(v0.z); o[3] = __float2bfloat16(v0.w);
      o[4] = __float2bfloat16(v1.x); o[5] = __float2bfloat16(v1.y);
      o[6] = __float2bfloat16(v1.z); o[7] = __float2bfloat16(v1.w);
    } else {
#pragma unroll
      for (int j = 0; j < 8; ++j) o[j] = __float2bfloat16(0.f);
    }
    *(uint4*)(hid_b + (size_t)r * KPAD + c8) = *(const uint4*)o;
  } else {
    int i = (bid - 6624) * 256 + tid;
    int d = i >> 11, tt = i & 2047;
    float inv = powf(150000.0f, -(float)d / 32.0f);
    float a = (float)positions[tt] * inv;
    cosT[i] = cosf(a);
    sinT[i] = sinf(a);
  }
}

// =====================================================================================
// 256x256 8-phase bf16 GEMM (T2 swizzle + T3/T4 counted vmcnt + T5 setprio)
// EPI=0: C f32 (C0/C1 by ksplit half). EPI=2: fused RoPE epilogue + woT-transpose tail.
// =====================================================================================
#define LDB(par) { \
  const char* _bb = lds + (((par)*4 + 2 + (wn>>1)) << 14); \
  _Pragma("unroll") \
  for (int _n = 0; _n < 4; ++_n) { \
    int _r = ((wn&1)<<6) + _n*16 + lm; \
    _Pragma("unroll") \
    for (int _kk = 0; _kk < 2; ++_kk) \
      bq[_n][_kk] = *(const bf16x8*)(_bb + _r*128 + (((_kk*4 + lg) ^ (_r & 7)) << 4)); } }

#define LDA(par, qc) { \
  const char* _ab = lds + (((par)*4 + wm) << 14); \
  _Pragma("unroll") \
  for (int _f = 0; _f < 2; ++_f) { \
    int _r = (qc)*32 + _f*16 + lm; \
    _Pragma("unroll") \
    for (int _kk = 0; _kk < 2; ++_kk) \
      af[_f][_kk] = *(const bf16x8*)(_ab + _r*128 + (((_kk*4 + lg) ^ (_r & 7)) << 4)); } }

#define MMQ(qc) \
  _Pragma("unroll") \
  for (int _kk = 0; _kk < 2; ++_kk) \
  _Pragma("unroll") \
  for (int _f = 0; _f < 2; ++_f) \
  _Pragma("unroll") \
  for (int _n = 0; _n < 4; ++_n) \
    acc[(qc)*2 + _f][_n] = __builtin_amdgcn_mfma_f32_16x16x32_bf16( \
        af[_f][_kk], bq[_n][_kk], acc[(qc)*2 + _f][_n], 0, 0, 0);

#define PHASE(qc, par, STMT, VMSTMT) { \
  bf16x8 af[2][2]; \
  if ((qc) == 0) { LDB(par); } \
  LDA(par, qc); \
  STMT \
  __builtin_amdgcn_s_barrier(); \
  asm volatile("s_waitcnt lgkmcnt(0)" ::: "memory"); \
  __builtin_amdgcn_sched_barrier(0); \
  __builtin_amdgcn_s_setprio(1); \
  MMQ(qc); \
  __builtin_amdgcn_s_setprio(0); \
  VMSTMT \
  __builtin_amdgcn_s_barrier(); }

template<int EPI>
__global__ __launch_bounds__(512, 2) void gemm256_k(
    const bf16* __restrict__ A, const bf16* __restrict__ BT,
    float* __restrict__ C0, float* __restrict__ C1,
    bf16* __restrict__ qb, bf16* __restrict__ kb, bf16* __restrict__ vT,
    const float* __restrict__ cosT, const float* __restrict__ sinT,
    const float* __restrict__ wo, bf16* __restrict__ woT,
    int N, int ldk, int nbn, int npair, int ksplit) {
  __shared__ __align__(16) char lds[131072];
  int tid = threadIdx.x;
  int bid = blockIdx.x;

  if (EPI == 2 && bid >= 160) {
    // ---- tail blocks: transpose w_o[4096][2880] -> woT[2880][QST], 2 tiles/block ----
    int i = bid - 160;
    int half = tid >> 8;
    int t = i * 2 + half;
    int tx = t % 45, ty = t / 45;
    int c0 = tx * 64, r0 = ty * 64;
    int tid2 = tid & 255;
    float* tb = (float*)lds + half * (64 * 68);
    int lr = tid2 >> 2, lc4 = (tid2 & 3) << 4;
    const float* s = wo + (size_t)(r0 + lr) * HIDDEN + c0 + lc4;
    *(float4*)&tb[lr * 68 + lc4 + 0]  = *(const float4*)(s + 0);
    *(float4*)&tb[lr * 68 + lc4 + 4]  = *(const float4*)(s + 4);
    *(float4*)&tb[lr * 68 + lc4 + 8]  = *(const float4*)(s + 8);
    *(float4*)&tb[lr * 68 + lc4 + 12] = *(const float4*)(s + 12);
    __syncthreads();
    int dr = tid2 >> 2;
#pragma unroll
    for (int rep = 0; rep < 2; ++rep) {
      int dc0 = (tid2 & 3) * 16 + rep * 8;
      bf16 o[8];
#pragma unroll
      for (int k = 0; k < 8; ++k) o[k] = __float2bfloat16(tb[(dc0 + k) * 68 + dr]);
      *(uint4*)(woT + (size_t)(c0 + dr) * QST + r0 + dc0) = *(const uint4*)o;
    }
    return;
  }

  int l = tid & 63, lg = l >> 4, lm = l & 15;
  int w = tid >> 6, wm = w >> 2, wn = w & 3;
  int kbeg = 0;
  float* C = C0;
  if (ksplit) {
    int half = gridDim.x >> 1;
    if (bid >= half) { bid -= half; kbeg = ksplit; C = C1; }
  }
  int bm = bid / nbn, bn = bid - bm * nbn;
  int m0 = bm << 8, n0 = bn << 8;
  int Bmax = N - 1;
  f32x4 acc[8][4] = {};
  bf16x8 bq[4][2];

  auto STG = [&](int slot, const bf16* mat, int rowBase, int rowMax, int kbase) {
#pragma unroll
    for (int rep = 0; rep < 2; ++rep) {
      int gi = (rep << 9) + tid;
      int row = gi >> 3, g = gi & 7;
      int gr = rowBase + row; if (gr > rowMax) gr = rowMax;
      gload16(mat + (size_t)gr * ldk + kbase + ((g ^ (row & 7)) << 3),
              lds + slot * 16384 + gi * 16);
    }
  };

  STG(0, A, m0, 2047, kbeg);
  STG(1, A, m0 + 128, 2047, kbeg);
  STG(2, BT, n0, Bmax, kbeg);
  STG(3, BT, n0 + 128, Bmax, kbeg);
  STG(6, BT, n0, Bmax, kbeg + 64);
  STG(7, BT, n0 + 128, Bmax, kbeg + 64);
  asm volatile("s_waitcnt vmcnt(4)" ::: "memory");
  __builtin_amdgcn_s_barrier();

  for (int i = 0; i < npair; ++i) {
    int kt = kbeg + (i << 7);
    bool pf = (i + 1 < npair);
    PHASE(0, 0, { STG(4, A, m0, 2047, kt + 64); }, ;)
    PHASE(1, 0, { STG(5, A, m0 + 128, 2047, kt + 64); }, ;)
    PHASE(2, 0, { if (pf) STG(2, BT, n0, Bmax, kt + 128); }, ;)
    PHASE(3, 0, { if (pf) STG(3, BT, n0 + 128, Bmax, kt + 128); },
          { if (pf) { asm volatile("s_waitcnt vmcnt(4)" ::: "memory"); }
            else    { asm volatile("s_waitcnt vmcnt(0)" ::: "memory"); } })
    PHASE(0, 1, { if (pf) STG(0, A, m0, 2047, kt + 128); }, ;)
    PHASE(1, 1, { if (pf) STG(1, A, m0 + 128, 2047, kt + 128); }, ;)
    PHASE(2, 1, { if (pf) STG(6, BT, n0, Bmax, kt + 192); }, ;)
    PHASE(3, 1, { if (pf) STG(7, BT, n0 + 128, Bmax, kt + 192); },
          { if (pf) { asm volatile("s_waitcnt vmcnt(4)" ::: "memory"); } })
  }

  if (EPI == 2) {
    // fused RoPE + layout epilogue. Wave owns head-slot h64 = bn*4 + wn.
    int h64 = (n0 >> 6) + wn;
    int tbase = m0 + (wm << 7) + lg * 4;
    if (h64 < 72) {
      bool isK = (h64 >= 64);
      bf16* outp = isK ? kb : qb;
      size_t ostr = isK ? 512 : QST;
      int hd0 = (isK ? (h64 - 64) : h64) << 6;
      float scl = isK ? 1.0f : 0.125f;
#pragma unroll
      for (int nf = 0; nf < 2; ++nf) {
        int d31 = nf * 16 + lm;
        const float* ct = cosT + (size_t)d31 * 2048;
        const float* st = sinT + (size_t)d31 * 2048;
#pragma unroll
        for (int mf = 0; mf < 8; ++mf) {
          int t0 = tbase + mf * 16;
          float4 c4 = *(const float4*)(ct + t0);
          float4 s4 = *(const float4*)(st + t0);
          float cc[4] = {c4.x, c4.y, c4.z, c4.w};
          float ss[4] = {s4.x, s4.y, s4.z, s4.w};
#pragma unroll
          for (int j = 0; j < 4; ++j) {
            float x1 = acc[mf][nf][j], x2 = acc[mf][nf + 2][j];
            outp[(size_t)(t0 + j) * ostr + hd0 + d31] =
                __float2bfloat16((x1 * cc[j] - x2 * ss[j]) * scl);
            outp[(size_t)(t0 + j) * ostr + hd0 + d31 + 32] =
                __float2bfloat16((x2 * cc[j] + x1 * ss[j]) * scl);
          }
        }
      }
    } else {
      int kvh = h64 - 72;
#pragma unroll
      for (int nf = 0; nf < 4; ++nf) {
        int d = nf * 16 + lm;
#pragma unroll
        for (int mf = 0; mf < 8; ++mf)
#pragma unroll
          for (int j = 0; j < 4; ++j) {
            int t = tbase + mf * 16 + j;
            int b = t >> 10, s = t & 1023;
            vT[((size_t)(b * 8 + kvh) * 64 + d) * 1024 + s] = __float2bfloat16(acc[mf][nf][j]);
          }
      }
    }
    return;
  }

#pragma unroll
  for (int mf = 0; mf < 8; ++mf)
#pragma unroll
    for (int nf = 0; nf < 4; ++nf) {
      int col = n0 + (wn << 6) + nf * 16 + lm;
      if (col >= N) continue;
      int row = m0 + (wm << 7) + mf * 16 + lg * 4;
#pragma unroll
      for (int j = 0; j < 4; ++j)
        C[(size_t)(row + j) * N + col] = acc[mf][nf][j];
    }
}

// ---------------- flash attention, sliding window 128, sinks ----------------
__global__ __launch_bounds__(256) void attn_k(const bf16* __restrict__ Q,
                                              const bf16* __restrict__ Kg,
                                              const bf16* __restrict__ VT,
                                              const float* __restrict__ sinks,
                                              bf16* __restrict__ Og) {
  __shared__ __align__(16) bf16 Qs[128 * 64];
  __shared__ __align__(16) bf16 Ks[128 * 64];
  __shared__ __align__(16) bf16 Vs[64 * 128];
  __shared__ __align__(16) bf16 Ps[4][32 * 128];
  int bid = blockIdx.x;
  int b = bid >> 9, rest = bid & 511, h = rest >> 3, qt = rest & 7;
  int q0 = qt * 128, kvh = h >> 3;
  int tid = threadIdx.x, w = tid >> 6, l = tid & 63, lg = l >> 4, lm = l & 15;

  float mrun[2][4], lrun[2][4];
  float ls = __logf(sinks[h]);
#pragma unroll
  for (int mi = 0; mi < 2; ++mi)
#pragma unroll
    for (int j = 0; j < 4; ++j) { mrun[mi][j] = ls; lrun[mi][j] = 1.0f; }
  f32x4 oacc[2][4] = {};

#pragma unroll
  for (int g = 0; g < 4; ++g) {
    int c = g * 256 + w * 64 + l;
    int r = c >> 3, kc = (c & 7) * 8;
    gload16(Q + ((size_t)(b * 1024 + q0 + r)) * QST + h * 64 + kc,
            (char*)Qs + (size_t)(g * 256 + w * 64) * 16);
  }

  for (int t = (q0 == 0) ? 1 : 0; t < 2; ++t) {
    int kb = q0 - 128 + t * 128;
#pragma unroll
    for (int g = 0; g < 4; ++g) {
      int c = g * 256 + w * 64 + l;
      int r = c >> 3, kc = (c & 7) * 8;
      gload16(Kg + ((size_t)(b * 1024 + kb + r)) * 512 + kvh * 64 + kc,
              (char*)Ks + (size_t)(g * 256 + w * 64) * 16);
      int rv = c >> 4, kv = (c & 15) * 8;
      gload16(VT + ((size_t)(b * 8 + kvh) * 64 + rv) * 1024 + kb + kv,
              (char*)Vs + (size_t)(g * 256 + w * 64) * 16);
    }
    __syncthreads();

    f32x4 sacc[2][8] = {};
#pragma unroll
    for (int kk = 0; kk < 2; ++kk) {
      bf16x8 qf[2], kf[8];
#pragma unroll
      for (int mi = 0; mi < 2; ++mi)
        qf[mi] = *reinterpret_cast<const bf16x8*>(&Qs[(w * 32 + mi * 16 + lm) * 64 + kk * 32 + lg * 8]);
#pragma unroll
      for (int ni = 0; ni < 8; ++ni)
        kf[ni] = *reinterpret_cast<const bf16x8*>(&Ks[(ni * 16 + lm) * 64 + kk * 32 + lg * 8]);
#pragma unroll
      for (int mi = 0; mi < 2; ++mi)
#pragma unroll
        for (int ni = 0; ni < 8; ++ni)
          sacc[mi][ni] = __builtin_amdgcn_mfma_f32_16x16x32_bf16(qf[mi], kf[ni], sacc[mi][ni], 0, 0, 0);
    }

#pragma unroll
    for (int mi = 0; mi < 2; ++mi)
#pragma unroll
      for (int j = 0; j < 4; ++j) {
        int qi = q0 + w * 32 + mi * 16 + lg * 4 + j;
        float mx = -1e30f;
#pragma unroll
        for (int ni = 0; ni < 8; ++ni) {
          int kg = kb + ni * 16 + lm;
          float v = sacc[mi][ni][j];
          v = (kg <= qi && kg >= qi - 127) ? v : -1e30f;
          sacc[mi][ni][j] = v;
          mx = fmaxf(mx, v);
        }
#pragma unroll
        for (int d = 1; d < 16; d <<= 1) mx = fmaxf(mx, __shfl_xor(mx, d, 64));
        float mnew = fmaxf(mrun[mi][j], mx);
        float sum = 0.f;
#pragma unroll
        for (int ni = 0; ni < 8; ++ni) {
          float p = __expf(sacc[mi][ni][j] - mnew);
          sacc[mi][ni][j] = p;
          sum += p;
        }
#pragma unroll
        for (int d = 1; d < 16; d <<= 1) sum += __shfl_xor(sum, d, 64);
        float alpha = __expf(mrun[mi][j] - mnew);
        lrun[mi][j] = lrun[mi][j] * alpha + sum;
        mrun[mi][j] = mnew;
#pragma unroll
        for (int ni = 0; ni < 4; ++ni) oacc[mi][ni][j] *= alpha;
#pragma unroll
        for (int ni = 0; ni < 8; ++ni)
          Ps[w][(mi * 16 + lg * 4 + j) * 128 + ni * 16 + lm] = __float2bfloat16(sacc[mi][ni][j]);
      }

#pragma unroll
    for (int ks = 0; ks < 4; ++ks) {
      bf16x8 pf[2], vf[4];
#pragma unroll
      for (int mi = 0; mi < 2; ++mi)
        pf[mi] = *reinterpret_cast<const bf16x8*>(&Ps[w][(mi * 16 + lm) * 128 + ks * 32 + lg * 8]);
#pragma unroll
      for (int ni = 0; ni < 4; ++ni)
        vf[ni] = *reinterpret_cast<const bf16x8*>(&Vs[(ni * 16 + lm) * 128 + ks * 32 + lg * 8]);
#pragma unroll
      for (int mi = 0; mi < 2; ++mi)
#pragma unroll
        for (int ni = 0; ni < 4; ++ni)
          oacc[mi][ni] = __builtin_amdgcn_mfma_f32_16x16x32_bf16(pf[mi], vf[ni], oacc[mi][ni], 0, 0, 0);
    }
    __syncthreads();
  }

#pragma unroll
  for (int mi = 0; mi < 2; ++mi)
#pragma unroll
    for (int ni = 0; ni < 4; ++ni)
#pragma unroll
      for (int j = 0; j < 4; ++j) {
        int tok = b * 1024 + q0 + w * 32 + mi * 16 + lg * 4 + j;
        Og[(size_t)tok * QST + h * 64 + ni * 16 + lm] =
            __float2bfloat16(oacc[mi][ni][j] / lrun[mi][j]);
      }
}

// ---------------- add two f32 partials -> f32 out ----------------
__global__ __launch_bounds__(256) void add2_k(const float* __restrict__ a,
                                              const float* __restrict__ b,
                                              float* __restrict__ o, int n4) {
  int i = blockIdx.x * 256 + threadIdx.x;
  if (i >= n4) return;
  float4 x = reinterpret_cast<const float4*>(a)[i];
  float4 y = reinterpret_cast<const float4*>(b)[i];
  reinterpret_cast<float4*>(o)[i] = make_float4(x.x + y.x, x.y + y.y, x.z + y.z, x.w + y.w);
}

extern "C" void kernel_launch(void* const* d_in, const int* in_sizes, int n_in,
                              void* d_out, int out_size, void* d_ws, size_t ws_size,
                              hipStream_t stream) {
  const int*   positions = (const int*)d_in[0];
  const float* hidden    = (const float*)d_in[1];
  const float* w_qkv     = (const float*)d_in[2];
  const float* w_o       = (const float*)d_in[3];
  const float* sinks     = (const float*)d_in[4];
  float* out = (float*)d_out;

  char* ws = (char*)d_ws;
  bf16*  wqkvT = (bf16*)(ws + 0);            // [5120][2944]  = 30,146,560 (dead after QKV)
  bf16*  woT   = (bf16*)(ws + 30146560);     // [2880][4160]  = 23,961,600
  bf16*  qb    = (bf16*)(ws + 54108160);     // [2048][4160]  = 17,039,360
  bf16*  kb    = (bf16*)(ws + 71147520);     // [2048][512]   =  2,097,152
  bf16*  vT    = (bf16*)(ws + 73244672);     // [16*64][1024] =  2,097,152
  bf16*  attnb = (bf16*)(ws + 75341824);     // [2048][4160]  = 17,039,360
  bf16*  hid_b = (bf16*)(ws + 92381184);     // [2048][2944]  = 12,058,624 (dead after QKV)
  float* cosT  = (float*)(ws + 104439808);   // 262,144 (dead after QKV)
  float* sinT  = (float*)(ws + 104701952);   // 262,144 (dead after QKV)
  float* Cp0   = (float*)(ws + 92381184);    // overlay hid_b/cosT/sinT: 23,592,960 -> ends 115,974,144
  float* Cp1   = (float*)(ws + 0);           // overlay wqkvT: 23,592,960

  // 1. fused prep: w_qkv transpose + hidden cvt/pad + sincos tables
  prep_k<<<6880, 256, 0, stream>>>(w_qkv, wqkvT, hidden, hid_b, positions, cosT, sinT);
  // 2. QKV projection + fused RoPE/layout epilogue; tail blocks transpose w_o -> woT
  gemm256_k<2><<<160 + 1440, 512, 0, stream>>>(
      hid_b, wqkvT, nullptr, nullptr, qb, kb, vT, cosT, sinT, w_o, woT,
      QKVN, KPAD, QKVN / 256, KPAD / 128, 0);
  // 3. attention
  attn_k<<<2 * NH * (SEQ / 128), 256, 0, stream>>>(qb, kb, vT, sinks, attnb);
  // 4. output projection with 2-way K-split -> 2 f32 partials (strides de-pow2'd)
  gemm256_k<0><<<2 * (NTOK / 256) * 12, 512, 0, stream>>>(
      attnb, woT, Cp0, Cp1, nullptr, nullptr, nullptr, nullptr, nullptr, nullptr, nullptr,
      HIDDEN, QST, 12, 16, 2048);
  // 5. partial sum -> out
  add2_k<<<(NTOK * HIDDEN / 4) / 256, 256, 0, stream>>>(Cp0, Cp1, out, NTOK * HIDDEN / 4);
}